// Round 6
// baseline (177.865 us; speedup 1.0000x reference)
//
#include <hip/hip_runtime.h>
#include <cstddef>

constexpr int FIN = 128;
constexpr int EPB = 2048;   // edges per block in sort pass (391 blocks)
constexpr int BSH = 7;      // bucket shift: 128 nodes per bucket
constexpr int NPB = 128;    // nodes per bucket
constexpr int PACK_SH = 25; // pack: (dst_local << 25) | src (src < 2^25)
constexpr int RSTR = 512;   // rows matrix stride (nbuck+1 <= 512)
constexpr int CAP = 4608;   // per-bucket edge cap for LDS staging (mean 2048)

typedef _Float16 half4 __attribute__((ext_vector_type(4)));
typedef _Float16 half8 __attribute__((ext_vector_type(8)));
typedef float floatx4 __attribute__((ext_vector_type(4)));

// ---------------------------------------------------------------------------
// Block-wide (256-thread) exclusive scan; also returns block total.
// ---------------------------------------------------------------------------
__device__ __forceinline__ int block_scan_tot(int v, int tid, int* wsums,
                                              int* tot) {
    int lane = tid & 63, w = tid >> 6;
    int x = v;
#pragma unroll
    for (int off = 1; off < 64; off <<= 1) {
        int y = __shfl_up(x, off, 64);
        if (lane >= off) x += y;
    }
    if (lane == 63) wsums[w] = x;
    __syncthreads();
    int add = 0;
#pragma unroll
    for (int i = 0; i < 4; ++i) add += (i < w) ? wsums[i] : 0;
    *tot = wsums[0] + wsums[1] + wsums[2] + wsums[3];
    return x + add - v;
}

// ---------------------------------------------------------------------------
// MFMA GEMM core: W-stage + sync + MFMA + fused AS/AD epilogue + Hh write.
// Assumes Xh[64][K+8] fp16 already populated (by stage or by fused agg).
// The __syncthreads() after W-stage orders any prior LDS writes (incl. the
// fused aggregate's X-tile writes) before the MFMA fragment reads.
// ---------------------------------------------------------------------------
template <int K>
__device__ __forceinline__
void gemm_core(const float* __restrict__ W, const float* __restrict__ ASRC,
               const float* __restrict__ ADST, _Float16* __restrict__ Hh,
               float* __restrict__ AS, float* __restrict__ AD, int N, int nb,
               _Float16* Xh, _Float16* WT) {
    constexpr int LDH = K + 8;
    const int tid = threadIdx.x;
    for (int i = tid; i < 64 * (K / 4); i += 256) {
        int n = i & 63, kg = i >> 6;
        half4 h;
#pragma unroll
        for (int j = 0; j < 4; ++j)
            h[j] = (_Float16)W[(4 * kg + j) * 64 + n];
        *(half4*)(WT + n * LDH + 4 * kg) = h;
    }
    __syncthreads();

    const int l = tid & 63;
    const int r0 = (tid >> 6) * 16;
    const int n16 = l & 15, quad = l >> 4;

    floatx4 acc[4];
#pragma unroll
    for (int nt = 0; nt < 4; ++nt) acc[nt] = (floatx4){0.f, 0.f, 0.f, 0.f};

#pragma unroll
    for (int k0 = 0; k0 < K; k0 += 32) {
        half8 a = *(const half8*)(Xh + (r0 + n16) * LDH + k0 + quad * 8);
#pragma unroll
        for (int nt = 0; nt < 4; ++nt) {
            half8 b = *(const half8*)(WT + (nt * 16 + n16) * LDH + k0 + quad * 8);
            acc[nt] = __builtin_amdgcn_mfma_f32_16x16x32_f16(a, b, acc[nt], 0, 0, 0);
        }
    }

    float pa[4] = {0.f, 0.f, 0.f, 0.f}, pd[4] = {0.f, 0.f, 0.f, 0.f};
#pragma unroll
    for (int nt = 0; nt < 4; ++nt) {
        float as_v = ASRC[nt * 16 + n16], ad_v = ADST[nt * 16 + n16];
#pragma unroll
        for (int reg = 0; reg < 4; ++reg) {
            pa[reg] += acc[nt][reg] * as_v;
            pd[reg] += acc[nt][reg] * ad_v;
        }
    }
#pragma unroll
    for (int off = 1; off < 16; off <<= 1) {
#pragma unroll
        for (int reg = 0; reg < 4; ++reg) {
            pa[reg] += __shfl_xor(pa[reg], off, 64);
            pd[reg] += __shfl_xor(pd[reg], off, 64);
        }
    }
    if (n16 == 0) {
#pragma unroll
        for (int reg = 0; reg < 4; ++reg) {
            int row = nb + r0 + quad * 4 + reg;
            if (row < N) { AS[row] = pa[reg]; AD[row] = pd[reg]; }
        }
    }

#pragma unroll
    for (int nt = 0; nt < 4; ++nt)
#pragma unroll
        for (int reg = 0; reg < 4; ++reg)
            Xh[(r0 + quad * 4 + reg) * LDH + nt * 16 + n16] = (_Float16)acc[nt][reg];
    {
        int r = r0 + (l >> 2);
        int o = (l & 3) * 16;
        if (nb + r < N) {
            half8 v0 = *(const half8*)(Xh + r * LDH + o);
            half8 v1 = *(const half8*)(Xh + r * LDH + o + 8);
            *(half8*)(Hh + (size_t)(nb + r) * 64 + o) = v0;
            *(half8*)(Hh + (size_t)(nb + r) * 64 + o + 8) = v1;
        }
    }
}

// gemm body with global X staging (layer 1)
template <int K, typename XT>
__device__ __forceinline__
void gemm_mfma_body(const XT* __restrict__ X, const float* __restrict__ W,
                    const float* __restrict__ ASRC, const float* __restrict__ ADST,
                    _Float16* __restrict__ Hh, float* __restrict__ AS,
                    float* __restrict__ AD, int N, int blk,
                    _Float16* Xh, _Float16* WT) {
    constexpr int LDH = K + 8;
    const int tid = threadIdx.x;
    const int nb = blk * 64;
    if constexpr (sizeof(XT) == 4) {
        constexpr int QPR = K / 4;
        for (int i = tid; i < 64 * QPR; i += 256) {
            int r = i / QPR, q = i % QPR;
            float4 v = make_float4(0.f, 0.f, 0.f, 0.f);
            if (nb + r < N) v = *(const float4*)(X + (size_t)(nb + r) * K + 4 * q);
            half4 h; h[0] = (_Float16)v.x; h[1] = (_Float16)v.y;
            h[2] = (_Float16)v.z; h[3] = (_Float16)v.w;
            *(half4*)(Xh + r * LDH + 4 * q) = h;
        }
    } else {
        constexpr int OPR = K / 8;
        for (int i = tid; i < 64 * OPR; i += 256) {
            int r = i / OPR, o = i % OPR;
            half8 v = {};
            if (nb + r < N) v = *(const half8*)(X + (size_t)(nb + r) * K + 8 * o);
            *(half8*)(Xh + r * LDH + 8 * o) = v;
        }
    }
    gemm_core<K>(W, ASRC, ADST, Hh, AS, AD, N, nb, Xh, WT);
}

// ---------------------------------------------------------------------------
// Dispatch 1: blocks [0, nblk) LDS-bucket-sort their 2048 edges into a
// block-PRIVATE ebuck slab (R2 lesson: scattered 4B cross-XCD writes are
// 16x amplified); emit cnts + rows. Rest: MFMA gemm layer-1. Block 0 resets
// the ticket used by bucket_colscan_fused.
// ---------------------------------------------------------------------------
__global__ __launch_bounds__(256)
void gemm1_and_sort(const float* __restrict__ X, const float* __restrict__ W,
                    const float* __restrict__ ASRC, const float* __restrict__ ADST,
                    _Float16* __restrict__ Hh, float* __restrict__ AS,
                    float* __restrict__ AD, int N,
                    const int* __restrict__ src, const int* __restrict__ dst,
                    int E, int nblk, int nbuck,
                    int* __restrict__ cnts, int* __restrict__ rows,
                    int* __restrict__ ebuck, int* __restrict__ ticket) {
    constexpr int K = FIN, LDH = K + 8;
    __shared__ _Float16 Xh[64 * LDH];
    __shared__ _Float16 WT[64 * LDH];
    __shared__ int wsums[4];

    const int tid = threadIdx.x;
    if ((int)blockIdx.x < nblk) {
        int* sorted = (int*)Xh;          // up to 2048 ints
        int* hist   = (int*)WT;          // 512 ints
        int* cur    = hist + 512;        // 512 ints
        if (blockIdx.x == 0 && tid == 0) *ticket = 0;
        for (int i = tid; i < nbuck; i += 256) hist[i] = 0;
        __syncthreads();

        const int e0 = blockIdx.x * EPB;
        const int e1 = min(e0 + EPB, E);
        const int cnt = e1 - e0;

        int pay[8], bk[8];
#pragma unroll
        for (int k = 0; k < 8; ++k) {
            int e = e0 + tid + k * 256;
            bk[k] = -1; pay[k] = 0;
            if (e < e1) {
                int d = dst[e];
                bk[k] = d >> BSH;
                pay[k] = ((d & (NPB - 1)) << PACK_SH) | src[e];
                atomicAdd(&hist[bk[k]], 1);
            }
        }
        __syncthreads();

        int i0 = 2 * tid, i1 = 2 * tid + 1;
        int v0 = (i0 < nbuck) ? hist[i0] : 0;
        int v1 = (i1 < nbuck) ? hist[i1] : 0;
        int tot;
        int ex = block_scan_tot(v0 + v1, tid, wsums, &tot);
        if (i0 < nbuck) {
            cur[i0] = ex;
            rows[blockIdx.x * RSTR + i0] = ex;
            cnts[blockIdx.x * nbuck + i0] = v0;
        }
        if (i1 < nbuck) {
            cur[i1] = ex + v0;
            rows[blockIdx.x * RSTR + i1] = ex + v0;
            cnts[blockIdx.x * nbuck + i1] = v1;
        }
        if (tid == 0) rows[blockIdx.x * RSTR + nbuck] = cnt;
        __syncthreads();

#pragma unroll
        for (int k = 0; k < 8; ++k) {
            if (bk[k] >= 0) {
                int p = atomicAdd(&cur[bk[k]], 1);
                sorted[p] = pay[k];
            }
        }
        __syncthreads();
        for (int i = tid; i < cnt; i += 256)
            ebuck[blockIdx.x * EPB + i] = sorted[i];
        return;
    }
    gemm_mfma_body<K, float>(X, W, ASRC, ADST, Hh, AS, AD, N,
                             blockIdx.x - nblk, Xh, WT);
}

// ---------------------------------------------------------------------------
// Dispatch 2: chunked column scan of cnts (391x391) + fused bucket-base scan
// in the last-arriving block (ticket pattern — deadlock-free, no spin).
// ---------------------------------------------------------------------------
__global__ __launch_bounds__(256)
void bucket_colscan_fused(int* __restrict__ cnts, int nblk, int nbuck,
                          int* __restrict__ btotal, int* __restrict__ bbase,
                          int* __restrict__ ticket) {
    __shared__ int wsums[4];
    __shared__ int lastflag;
    int b = blockIdx.x;
    int tid = threadIdx.x;
    int carry = 0;
    for (int c0 = 0; c0 < nblk; c0 += 256) {
        int t = c0 + tid;
        int v = (t < nblk) ? cnts[t * nbuck + b] : 0;
        int tot;
        int e = block_scan_tot(v, tid, wsums, &tot);
        if (t < nblk) cnts[t * nbuck + b] = e + carry;
        carry += tot;
        __syncthreads();
    }
    if (tid == 0) {
        atomicExch(&btotal[b], carry);
        int old = atomicAdd(ticket, 1);
        lastflag = (old == nbuck - 1);
    }
    __syncthreads();
    if (!lastflag) return;
    int i0 = 2 * tid, i1 = 2 * tid + 1;
    int v0 = (i0 < nbuck) ? atomicAdd(&btotal[i0], 0) : 0;
    int v1 = (i1 < nbuck) ? atomicAdd(&btotal[i1], 0) : 0;
    __syncthreads();
    int tot2;
    int e2 = block_scan_tot(v0 + v1, tid, wsums, &tot2);
    if (i0 <= nbuck) bbase[i0] = e2;
    if (i1 <= nbuck) bbase[i1] = e2 + v0;
}

// ---------------------------------------------------------------------------
// Dispatch 3: bucket b -> CSR. Gather bucket b's segments from the 391
// private slabs into LDS (block-major order), then node-hist/scan/scatter.
// All global writes are block-private.
// ---------------------------------------------------------------------------
__global__ __launch_bounds__(256)
void bucket_to_csr(const int* __restrict__ ebuck, const int* __restrict__ rows,
                   const int* __restrict__ cnts, const int* __restrict__ bbase,
                   int N, int E, int nblk, int nbuck,
                   int* __restrict__ row_ptr, int* __restrict__ csr_src) {
    __shared__ int eL[CAP];
    __shared__ int hist[NPB];
    __shared__ int cur[NPB];
    __shared__ int wsums[4];
    const int b = blockIdx.x, tid = threadIdx.x;
    const int nstart = b << BSH;
    const int base = bbase[b], endp = bbase[b + 1];
    const int btot = endp - base;

    if (tid < NPB) hist[tid] = 0;
    for (int blk = tid; blk < nblk; blk += 256) {
        int r0 = rows[blk * RSTR + b];
        int r1 = rows[blk * RSTR + b + 1];
        int c0 = cnts[blk * nbuck + b];
        for (int i = 0; i < r1 - r0; ++i) {
            int c = c0 + i;
            if (c < CAP) eL[c] = ebuck[blk * EPB + r0 + i];
        }
    }
    __syncthreads();

    for (int e = tid; e < btot; e += 256)
        atomicAdd(&hist[((unsigned)eL[e]) >> PACK_SH], 1);
    __syncthreads();
    int v = (tid < NPB) ? hist[tid] : 0;
    int tot;
    int excl = block_scan_tot(v, tid, wsums, &tot);
    if (tid < NPB) {
        cur[tid] = excl;
        if (nstart + tid < N) row_ptr[nstart + tid] = base + excl;
    }
    if (b == 0 && tid == 0) row_ptr[N] = E;
    __syncthreads();
    for (int e = tid; e < btot; e += 256) {
        int pv = eL[e];
        int p = atomicAdd(&cur[((unsigned)pv) >> PACK_SH], 1);
        csr_src[base + p] = pv & ((1 << PACK_SH) - 1);
    }
}

// ---------------------------------------------------------------------------
// Single-node full-wave aggregation (deg > 32 fallback, incl. deg > 64).
// LDSOUT: write node's 64-ch fp16 row into ldsrow instead of global OUT.
// ---------------------------------------------------------------------------
template <bool LDSOUT, typename OT>
__device__ __forceinline__
void agg_one_node(const _Float16* __restrict__ Hh, const float* __restrict__ AS,
                  const float* __restrict__ AD, const int* __restrict__ csr_src,
                  const float* __restrict__ bias, OT* __restrict__ OUT,
                  _Float16* ldsrow, int n, int base, int end, int lane, int relu) {
    const int cnt = end - base;
    const float adn = AD[n];

    if (cnt > 64) {   // rare scalar 2-pass path
        float m = -INFINITY;
        for (int c0 = base; c0 < end; c0 += 64) {
            int c = min(64, end - c0);
            float e = -INFINITY;
            if (lane < c) {
                int sr = csr_src[c0 + lane];
                float t = AS[sr] + adn;
                e = t > 0.f ? t : 0.2f * t;
            }
#pragma unroll
            for (int off = 32; off > 0; off >>= 1) e = fmaxf(e, __shfl_xor(e, off, 64));
            m = fmaxf(m, e);
        }
        float s = 0.f, acc = 0.f;
        for (int c0 = base; c0 < end; c0 += 64) {
            int c = min(64, end - c0);
            int srcl = 0;
            float p = 0.f;
            if (lane < c) {
                srcl = csr_src[c0 + lane];
                float t = AS[srcl] + adn;
                t = t > 0.f ? t : 0.2f * t;
                p = __expf(t - m);
            }
            float cs = p;
#pragma unroll
            for (int off = 32; off > 0; off >>= 1) cs += __shfl_xor(cs, off, 64);
            s += cs;
            for (int j = 0; j < c; ++j)
                acc += __shfl(p, j, 64) *
                       (float)Hh[(size_t)__shfl(srcl, j, 64) * 64 + lane];
        }
        float o = acc * (1.f / (s + 1e-16f)) + bias[lane];
        if (relu) o = fmaxf(o, 0.f);
        if constexpr (LDSOUT) ldsrow[lane] = (_Float16)o;
        else OUT[(size_t)n * 64 + lane] = (OT)o;
        return;
    }

    // deg <= 64 full-wave path
    int srcl = 0;
    float el = 0.f;
    if (lane < cnt) {
        srcl = csr_src[base + lane];
        float e = AS[srcl] + adn;
        el = e > 0.f ? e : 0.2f * e;
    }
    float p = (lane < cnt) ? __expf(el) : 0.f;
    float s = p;
#pragma unroll
    for (int off = 32; off > 0; off >>= 1) s += __shfl_xor(s, off, 64);
    const float inv = 1.f / (s + 1e-16f);

    const int eg = lane >> 3;
    const int c8 = (lane & 7) * 8;

    float acc[8], acc2[8];
#pragma unroll
    for (int t = 0; t < 8; ++t) { acc[t] = 0.f; acc2[t] = 0.f; }

    int j = 0;
    for (; j + 16 <= cnt; j += 16) {
        int iA = j + eg, iB = j + 8 + eg;
        int sA = __shfl(srcl, iA, 64), sB = __shfl(srcl, iB, 64);
        float aA = __shfl(p, iA, 64),  aB = __shfl(p, iB, 64);
        half8 hA = *(const half8*)(Hh + (size_t)sA * 64 + c8);
        half8 hB = *(const half8*)(Hh + (size_t)sB * 64 + c8);
#pragma unroll
        for (int t = 0; t < 8; ++t) {
            acc[t]  += aA * (float)hA[t];
            acc2[t] += aB * (float)hB[t];
        }
    }
    for (; j < cnt; j += 8) {
        int iA = j + eg;
        int sA = __shfl(srcl, iA, 64);
        float aA = __shfl(p, iA, 64);
        half8 hA = *(const half8*)(Hh + (size_t)sA * 64 + c8);
#pragma unroll
        for (int t = 0; t < 8; ++t) acc[t] += aA * (float)hA[t];
    }
#pragma unroll
    for (int t = 0; t < 8; ++t) acc[t] += acc2[t];
#pragma unroll
    for (int off = 8; off <= 32; off <<= 1)
#pragma unroll
        for (int t = 0; t < 8; ++t) acc[t] += __shfl_xor(acc[t], off, 64);

    if (lane < 8) {
        float4 b0 = *(const float4*)(bias + c8);
        float4 b1 = *(const float4*)(bias + c8 + 4);
        float o[8];
        o[0] = acc[0] * inv + b0.x; o[1] = acc[1] * inv + b0.y;
        o[2] = acc[2] * inv + b0.z; o[3] = acc[3] * inv + b0.w;
        o[4] = acc[4] * inv + b1.x; o[5] = acc[5] * inv + b1.y;
        o[6] = acc[6] * inv + b1.z; o[7] = acc[7] * inv + b1.w;
        if (relu) {
#pragma unroll
            for (int t = 0; t < 8; ++t) o[t] = fmaxf(o[t], 0.f);
        }
        if constexpr (LDSOUT) {
            half8 hv;
#pragma unroll
            for (int t = 0; t < 8; ++t) hv[t] = (_Float16)o[t];
            *(half8*)(ldsrow + c8) = hv;
        } else if constexpr (sizeof(OT) == 2) {
            half8 hv;
#pragma unroll
            for (int t = 0; t < 8; ++t) hv[t] = (_Float16)o[t];
            *(half8*)((_Float16*)OUT + (size_t)n * 64 + c8) = hv;
        } else {
            *(float4*)((float*)OUT + (size_t)n * 64 + c8) =
                make_float4(o[0], o[1], o[2], o[3]);
            *(float4*)((float*)OUT + (size_t)n * 64 + c8 + 4) =
                make_float4(o[4], o[5], o[6], o[7]);
        }
    }
}

// ---------------------------------------------------------------------------
// Paired (2 nodes per wave) softmax+aggregate; deg<=32 fast path.
// LDSOUT: fp16 rows go to ldsX[(n-tile0)*72 + c] (layer-2 X tile).
// ---------------------------------------------------------------------------
template <bool LDSOUT, typename OT>
__device__ __forceinline__
void agg_pair(const _Float16* __restrict__ Hh, const float* __restrict__ AS,
              const float* __restrict__ AD, const int* __restrict__ row_ptr,
              const int* __restrict__ csr_src, const float* __restrict__ bias,
              OT* __restrict__ OUT, _Float16* ldsX, int tile0,
              int pair0, int N, int relu, int lane) {
    const int half = lane >> 5;
    const int l32  = lane & 31;
    const int n = pair0 + half;

    int base = 0, end = 0;
    if (n < N) { base = row_ptr[n]; end = row_ptr[n + 1]; }
    const int cnt = end - base;

    if (!__all(cnt <= 32)) {
        int baseA = __shfl(base, 0, 64),  endA = __shfl(end, 0, 64);
        int baseB = __shfl(base, 32, 64), endB = __shfl(end, 32, 64);
        agg_one_node<LDSOUT, OT>(Hh, AS, AD, csr_src, bias, OUT,
                                 LDSOUT ? ldsX + (pair0 - tile0) * 72 : nullptr,
                                 pair0, baseA, endA, lane, relu);
        if (pair0 + 1 < N)
            agg_one_node<LDSOUT, OT>(Hh, AS, AD, csr_src, bias, OUT,
                                     LDSOUT ? ldsX + (pair0 + 1 - tile0) * 72 : nullptr,
                                     pair0 + 1, baseB, endB, lane, relu);
        return;
    }

    const float adn = (n < N) ? AD[n] : 0.f;
    int srcl = 0;
    float p = 0.f;
    if (l32 < cnt) {
        srcl = csr_src[base + l32];
        float e = AS[srcl] + adn;
        e = e > 0.f ? e : 0.2f * e;
        p = __expf(e);
    }
    float s = p;
#pragma unroll
    for (int off = 16; off > 0; off >>= 1) s += __shfl_xor(s, off, 64);
    const float inv = 1.f / (s + 1e-16f);

    const int eg = l32 >> 3;
    const int c8 = (l32 & 7) * 8;

    float acc[8], acc2[8];
#pragma unroll
    for (int t = 0; t < 8; ++t) { acc[t] = 0.f; acc2[t] = 0.f; }

    int j = 0;
    for (; j + 8 <= cnt; j += 8) {
        int iA = j + eg, iB = j + 4 + eg;
        int sA = __shfl(srcl, iA, 32), sB = __shfl(srcl, iB, 32);
        float aA = __shfl(p, iA, 32),  aB = __shfl(p, iB, 32);
        half8 hA = *(const half8*)(Hh + (size_t)sA * 64 + c8);
        half8 hB = *(const half8*)(Hh + (size_t)sB * 64 + c8);
#pragma unroll
        for (int t = 0; t < 8; ++t) {
            acc[t]  += aA * (float)hA[t];
            acc2[t] += aB * (float)hB[t];
        }
    }
    for (; j < cnt; j += 4) {
        int iA = j + eg;
        int sA = __shfl(srcl, iA, 32);
        float aA = __shfl(p, iA, 32);
        half8 hA = *(const half8*)(Hh + (size_t)sA * 64 + c8);
#pragma unroll
        for (int t = 0; t < 8; ++t) acc[t] += aA * (float)hA[t];
    }
#pragma unroll
    for (int t = 0; t < 8; ++t) acc[t] += acc2[t];
#pragma unroll
    for (int t = 0; t < 8; ++t) acc[t] += __shfl_xor(acc[t], 8, 64);
#pragma unroll
    for (int t = 0; t < 8; ++t) acc[t] += __shfl_xor(acc[t], 16, 64);

    if (l32 < 8 && n < N) {
        float4 b0 = *(const float4*)(bias + c8);
        float4 b1 = *(const float4*)(bias + c8 + 4);
        float o[8];
        o[0] = acc[0] * inv + b0.x; o[1] = acc[1] * inv + b0.y;
        o[2] = acc[2] * inv + b0.z; o[3] = acc[3] * inv + b0.w;
        o[4] = acc[4] * inv + b1.x; o[5] = acc[5] * inv + b1.y;
        o[6] = acc[6] * inv + b1.z; o[7] = acc[7] * inv + b1.w;
        if (relu) {
#pragma unroll
            for (int t = 0; t < 8; ++t) o[t] = fmaxf(o[t], 0.f);
        }
        if constexpr (LDSOUT) {
            half8 hv;
#pragma unroll
            for (int t = 0; t < 8; ++t) hv[t] = (_Float16)o[t];
            *(half8*)(ldsX + (n - tile0) * 72 + c8) = hv;
        } else if constexpr (sizeof(OT) == 2) {
            half8 hv;
#pragma unroll
            for (int t = 0; t < 8; ++t) hv[t] = (_Float16)o[t];
            *(half8*)((_Float16*)OUT + (size_t)n * 64 + c8) = hv;
        } else {
            *(float4*)((float*)OUT + (size_t)n * 64 + c8) =
                make_float4(o[0], o[1], o[2], o[3]);
            *(float4*)((float*)OUT + (size_t)n * 64 + c8 + 4) =
                make_float4(o[4], o[5], o[6], o[7]);
        }
    }
}

// ---------------------------------------------------------------------------
// Dispatch 4 (fused): aggregate layer-1 for this block's 64-node tile
// directly into the LDS X-tile (fp16, relu), then MFMA gemm layer-2.
// Removes the R1h global round-trip and one dispatch boundary. No
// inter-block sync anywhere — each block touches only its own tile.
// NOTE: q-loop is unroll 1 — R4/R5 lesson: 8x force-inlined agg_pair
// (16 copies of agg_one_node) blows up the build.
// ---------------------------------------------------------------------------
__global__ __launch_bounds__(256)
void agg1_gemm2(const _Float16* __restrict__ Hh1, const float* __restrict__ AS1,
                const float* __restrict__ AD1, const int* __restrict__ row_ptr,
                const int* __restrict__ csr_src, const float* __restrict__ b1,
                const float* __restrict__ W2, const float* __restrict__ as2w,
                const float* __restrict__ ad2w, _Float16* __restrict__ Hh2,
                float* __restrict__ AS2, float* __restrict__ AD2, int N) {
    constexpr int K = 64, LDH = K + 8;   // 72
    __shared__ _Float16 Xh[64 * LDH];
    __shared__ _Float16 WT[64 * LDH];
    const int tid = threadIdx.x;
    const int tile0 = blockIdx.x * 64;

    for (int i = tid; i < 64 * LDH / 8; i += 256)
        ((half8*)Xh)[i] = (half8){};
    __syncthreads();

    const int lane = tid & 63, w = tid >> 6;
#pragma unroll 1
    for (int q = 0; q < 8; ++q) {
        int pair0 = tile0 + (w * 8 + q) * 2;
        if (pair0 < N)
            agg_pair<true, _Float16>(Hh1, AS1, AD1, row_ptr, csr_src, b1,
                                     (_Float16*)nullptr, Xh, tile0,
                                     pair0, N, 1, lane);
    }
    // gemm_core's post-W-stage __syncthreads orders agg LDS writes before MFMA
    gemm_core<K>(W2, as2w, ad2w, Hh2, AS2, AD2, N, tile0, Xh, WT);
}

// ---------------------------------------------------------------------------
// Dispatch 5: standalone paired aggregate (layer 2, fp32 out).
// ---------------------------------------------------------------------------
template <typename OT>
__global__ __launch_bounds__(256)
void gat_aggregate(const _Float16* __restrict__ Hh, const float* __restrict__ AS,
                   const float* __restrict__ AD, const int* __restrict__ row_ptr,
                   const int* __restrict__ csr_src, const float* __restrict__ bias,
                   OT* __restrict__ OUT, int N, int relu) {
    const int lane = threadIdx.x & 63;
    const int pair0 = blockIdx.x * 8 + (threadIdx.x >> 6) * 2;
    if (pair0 >= N) return;
    agg_pair<false, OT>(Hh, AS, AD, row_ptr, csr_src, bias, OUT,
                        (_Float16*)nullptr, 0, pair0, N, relu, lane);
}

// ---------------------------------------------------------------------------
extern "C" void kernel_launch(void* const* d_in, const int* in_sizes, int n_in,
                              void* d_out, int out_size, void* d_ws, size_t ws_size,
                              hipStream_t stream) {
    const float* x    = (const float*)d_in[0];
    const int*   ei   = (const int*)d_in[1];
    const float* W1   = (const float*)d_in[2];
    const float* as1w = (const float*)d_in[3];
    const float* ad1w = (const float*)d_in[4];
    const float* b1   = (const float*)d_in[5];
    const float* W2   = (const float*)d_in[6];
    const float* as2w = (const float*)d_in[7];
    const float* ad2w = (const float*)d_in[8];
    const float* b2   = (const float*)d_in[9];
    float* out = (float*)d_out;

    const int N = in_sizes[0] / FIN;   // 50000
    const int E = in_sizes[1] / 2;     // 800000
    const int* esrc = ei;
    const int* edst = ei + E;

    const int nbuck = (N + NPB - 1) >> BSH;      // 391
    const int nblk  = (E + EPB - 1) / EPB;       // 391

    char* wp8 = (char*)d_ws;
    _Float16* Hh  = (_Float16*)wp8;  wp8 += (size_t)N * 64 * 2;   // layer-1 h
    _Float16* H2h = (_Float16*)wp8;  wp8 += (size_t)N * 64 * 2;   // layer-2 h
    float* AS1 = (float*)wp8;        wp8 += (size_t)N * 4;
    float* AD1 = (float*)wp8;        wp8 += (size_t)N * 4;
    float* AS2 = (float*)wp8;        wp8 += (size_t)N * 4;
    float* AD2 = (float*)wp8;        wp8 += (size_t)N * 4;
    int* row_ptr = (int*)wp8;        wp8 += (size_t)(N + 1) * 4;
    int* csr     = (int*)wp8;        wp8 += (size_t)E * 4;
    int* ebuck   = (int*)wp8;        wp8 += (size_t)nblk * EPB * 4;
    int* cnts    = (int*)wp8;        wp8 += (size_t)nblk * nbuck * 4;
    int* rows    = (int*)wp8;        wp8 += (size_t)nblk * RSTR * 4;
    int* btotal  = (int*)wp8;        wp8 += (size_t)nbuck * 4;
    int* bbase   = (int*)wp8;        wp8 += (size_t)(nbuck + 1) * 4;
    int* ticket  = (int*)wp8;        wp8 += 4;

    const int nbG = (N + 63) / 64;               // 782
    const int nbAgg = (N + 7) / 8;               // 6250

    // 1) fused: LDS bucket-sort (391 blocks) + MFMA gemm layer-1
    hipLaunchKernelGGL(gemm1_and_sort, dim3(nblk + nbG), dim3(256), 0, stream,
                       x, W1, as1w, ad1w, Hh, AS1, AD1, N,
                       esrc, edst, E, nblk, nbuck, cnts, rows, ebuck, ticket);
    // 2) chunked column scan + fused bucket-base scan (ticket, no spin)
    hipLaunchKernelGGL(bucket_colscan_fused, dim3(nbuck), dim3(256), 0, stream,
                       cnts, nblk, nbuck, btotal, bbase, ticket);
    // 3) gather private slabs -> LDS -> node-sorted CSR
    hipLaunchKernelGGL(bucket_to_csr, dim3(nbuck), dim3(256), 0, stream,
                       ebuck, rows, cnts, bbase, N, E, nblk, nbuck, row_ptr, csr);
    // 4) fused: aggregate layer-1 (into LDS) + MFMA gemm layer-2
    hipLaunchKernelGGL(agg1_gemm2, dim3(nbG), dim3(256), 0, stream,
                       Hh, AS1, AD1, row_ptr, csr, b1,
                       W2, as2w, ad2w, H2h, AS2, AD2, N);
    // 5) aggregate layer-2 (fp32 out)
    hipLaunchKernelGGL(gat_aggregate<float>, dim3(nbAgg), dim3(256), 0,
                       stream, H2h, AS2, AD2, row_ptr, csr, b2, out, N, 0);
}

// Round 7
// 162.729 us; speedup vs baseline: 1.0930x; 1.0930x over previous
//
#include <hip/hip_runtime.h>
#include <cstddef>

constexpr int FIN = 128;
constexpr int EPB = 2048;   // edges per block in sort pass (391 blocks)
constexpr int BSH = 7;      // bucket shift: 128 nodes per bucket
constexpr int NPB = 128;    // nodes per bucket
constexpr int PACK_SH = 25; // pack: (dst_local << 25) | src (src < 2^25)
constexpr int SRCMASK = (1 << PACK_SH) - 1;
constexpr int RSTR = 512;   // rows matrix stride (nbuck+1 <= 512)
constexpr int CAP = 4608;   // per-bucket edge cap (mean 2048, sd ~45)
constexpr int RPS = NPB + 1; // per-bucket row-table stride (129)

typedef _Float16 half4 __attribute__((ext_vector_type(4)));
typedef _Float16 half8 __attribute__((ext_vector_type(8)));
typedef float floatx4 __attribute__((ext_vector_type(4)));

// ---------------------------------------------------------------------------
// Block-wide exclusive scan over NW waves (NW*64 threads); returns total.
// ---------------------------------------------------------------------------
template <int NW>
__device__ __forceinline__ int block_scan_tot(int v, int tid, int* wsums,
                                              int* tot) {
    int lane = tid & 63, w = tid >> 6;
    int x = v;
#pragma unroll
    for (int off = 1; off < 64; off <<= 1) {
        int y = __shfl_up(x, off, 64);
        if (lane >= off) x += y;
    }
    if (lane == 63) wsums[w] = x;
    __syncthreads();
    int add = 0, t = 0;
#pragma unroll
    for (int i = 0; i < NW; ++i) {
        add += (i < w) ? wsums[i] : 0;
        t += wsums[i];
    }
    *tot = t;
    return x + add - v;
}

// ---------------------------------------------------------------------------
// MFMA GEMM core: W-stage + sync + MFMA + fused AS/AD epilogue + Hh write.
// ---------------------------------------------------------------------------
template <int K>
__device__ __forceinline__
void gemm_core(const float* __restrict__ W, const float* __restrict__ ASRC,
               const float* __restrict__ ADST, _Float16* __restrict__ Hh,
               float* __restrict__ AS, float* __restrict__ AD, int N, int nb,
               _Float16* Xh, _Float16* WT) {
    constexpr int LDH = K + 8;
    const int tid = threadIdx.x;
    for (int i = tid; i < 64 * (K / 4); i += 256) {
        int n = i & 63, kg = i >> 6;
        half4 h;
#pragma unroll
        for (int j = 0; j < 4; ++j)
            h[j] = (_Float16)W[(4 * kg + j) * 64 + n];
        *(half4*)(WT + n * LDH + 4 * kg) = h;
    }
    __syncthreads();

    const int l = tid & 63;
    const int r0 = (tid >> 6) * 16;
    const int n16 = l & 15, quad = l >> 4;

    floatx4 acc[4];
#pragma unroll
    for (int nt = 0; nt < 4; ++nt) acc[nt] = (floatx4){0.f, 0.f, 0.f, 0.f};

#pragma unroll
    for (int k0 = 0; k0 < K; k0 += 32) {
        half8 a = *(const half8*)(Xh + (r0 + n16) * LDH + k0 + quad * 8);
#pragma unroll
        for (int nt = 0; nt < 4; ++nt) {
            half8 b = *(const half8*)(WT + (nt * 16 + n16) * LDH + k0 + quad * 8);
            acc[nt] = __builtin_amdgcn_mfma_f32_16x16x32_f16(a, b, acc[nt], 0, 0, 0);
        }
    }

    float pa[4] = {0.f, 0.f, 0.f, 0.f}, pd[4] = {0.f, 0.f, 0.f, 0.f};
#pragma unroll
    for (int nt = 0; nt < 4; ++nt) {
        float as_v = ASRC[nt * 16 + n16], ad_v = ADST[nt * 16 + n16];
#pragma unroll
        for (int reg = 0; reg < 4; ++reg) {
            pa[reg] += acc[nt][reg] * as_v;
            pd[reg] += acc[nt][reg] * ad_v;
        }
    }
#pragma unroll
    for (int off = 1; off < 16; off <<= 1) {
#pragma unroll
        for (int reg = 0; reg < 4; ++reg) {
            pa[reg] += __shfl_xor(pa[reg], off, 64);
            pd[reg] += __shfl_xor(pd[reg], off, 64);
        }
    }
    if (n16 == 0) {
#pragma unroll
        for (int reg = 0; reg < 4; ++reg) {
            int row = nb + r0 + quad * 4 + reg;
            if (row < N) { AS[row] = pa[reg]; AD[row] = pd[reg]; }
        }
    }

#pragma unroll
    for (int nt = 0; nt < 4; ++nt)
#pragma unroll
        for (int reg = 0; reg < 4; ++reg)
            Xh[(r0 + quad * 4 + reg) * LDH + nt * 16 + n16] = (_Float16)acc[nt][reg];
    {
        int r = r0 + (l >> 2);
        int o = (l & 3) * 16;
        if (nb + r < N) {
            half8 v0 = *(const half8*)(Xh + r * LDH + o);
            half8 v1 = *(const half8*)(Xh + r * LDH + o + 8);
            *(half8*)(Hh + (size_t)(nb + r) * 64 + o) = v0;
            *(half8*)(Hh + (size_t)(nb + r) * 64 + o + 8) = v1;
        }
    }
}

// gemm body with global X staging
template <int K, typename XT>
__device__ __forceinline__
void gemm_mfma_body(const XT* __restrict__ X, const float* __restrict__ W,
                    const float* __restrict__ ASRC, const float* __restrict__ ADST,
                    _Float16* __restrict__ Hh, float* __restrict__ AS,
                    float* __restrict__ AD, int N, int blk,
                    _Float16* Xh, _Float16* WT) {
    constexpr int LDH = K + 8;
    const int tid = threadIdx.x;
    const int nb = blk * 64;
    if constexpr (sizeof(XT) == 4) {
        constexpr int QPR = K / 4;
        for (int i = tid; i < 64 * QPR; i += 256) {
            int r = i / QPR, q = i % QPR;
            float4 v = make_float4(0.f, 0.f, 0.f, 0.f);
            if (nb + r < N) v = *(const float4*)(X + (size_t)(nb + r) * K + 4 * q);
            half4 h; h[0] = (_Float16)v.x; h[1] = (_Float16)v.y;
            h[2] = (_Float16)v.z; h[3] = (_Float16)v.w;
            *(half4*)(Xh + r * LDH + 4 * q) = h;
        }
    } else {
        constexpr int OPR = K / 8;
        for (int i = tid; i < 64 * OPR; i += 256) {
            int r = i / OPR, o = i % OPR;
            half8 v = {};
            if (nb + r < N) v = *(const half8*)(X + (size_t)(nb + r) * K + 8 * o);
            *(half8*)(Xh + r * LDH + 8 * o) = v;
        }
    }
    gemm_core<K>(W, ASRC, ADST, Hh, AS, AD, N, nb, Xh, WT);
}

// ---------------------------------------------------------------------------
// Dispatch 1: blocks [0, nblk) LDS-bucket-sort their 2048 edges into a
// block-PRIVATE ebuck slab (R2 lesson: scattered 4B cross-XCD writes are
// 16x amplified) and emit the per-(blk,bucket) offsets (rows). No cnts /
// colscan anymore — global CSR offsets are never needed (bucket slabs are
// padded). Rest: MFMA gemm layer-1.
// ---------------------------------------------------------------------------
__global__ __launch_bounds__(256)
void gemm1_and_sort(const float* __restrict__ X, const float* __restrict__ W,
                    const float* __restrict__ ASRC, const float* __restrict__ ADST,
                    _Float16* __restrict__ Hh, float* __restrict__ AS,
                    float* __restrict__ AD, int N,
                    const int* __restrict__ src, const int* __restrict__ dst,
                    int E, int nblk, int nbuck,
                    int* __restrict__ rows, int* __restrict__ ebuck) {
    constexpr int K = FIN, LDH = K + 8;
    __shared__ _Float16 Xh[64 * LDH];
    __shared__ _Float16 WT[64 * LDH];
    __shared__ int wsums[4];

    const int tid = threadIdx.x;
    if ((int)blockIdx.x < nblk) {
        int* sorted = (int*)Xh;          // up to 2048 ints
        int* hist   = (int*)WT;          // 512 ints
        int* cur    = hist + 512;        // 512 ints
        for (int i = tid; i < nbuck; i += 256) hist[i] = 0;
        __syncthreads();

        const int e0 = blockIdx.x * EPB;
        const int e1 = min(e0 + EPB, E);
        const int cnt = e1 - e0;

        int pay[8], bk[8];
#pragma unroll
        for (int k = 0; k < 8; ++k) {
            int e = e0 + tid + k * 256;
            bk[k] = -1; pay[k] = 0;
            if (e < e1) {
                int d = dst[e];
                bk[k] = d >> BSH;
                pay[k] = ((d & (NPB - 1)) << PACK_SH) | src[e];
                atomicAdd(&hist[bk[k]], 1);
            }
        }
        __syncthreads();

        int i0 = 2 * tid, i1 = 2 * tid + 1;
        int v0 = (i0 < nbuck) ? hist[i0] : 0;
        int v1 = (i1 < nbuck) ? hist[i1] : 0;
        int tot;
        int ex = block_scan_tot<4>(v0 + v1, tid, wsums, &tot);
        if (i0 < nbuck) {
            cur[i0] = ex;
            rows[blockIdx.x * RSTR + i0] = ex;
        }
        if (i1 < nbuck) {
            cur[i1] = ex + v0;
            rows[blockIdx.x * RSTR + i1] = ex + v0;
        }
        if (tid == 0) rows[blockIdx.x * RSTR + nbuck] = cnt;
        __syncthreads();

#pragma unroll
        for (int k = 0; k < 8; ++k) {
            if (bk[k] >= 0) {
                int p = atomicAdd(&cur[bk[k]], 1);
                sorted[p] = pay[k];
            }
        }
        __syncthreads();
        for (int i = tid; i < cnt; i += 256)
            ebuck[blockIdx.x * EPB + i] = sorted[i];
        return;
    }
    gemm_mfma_body<K, float>(X, W, ASRC, ADST, Hh, AS, AD, N,
                             blockIdx.x - nblk, Xh, WT);
}

template <int K, typename XT>
__global__ __launch_bounds__(256)
void gemm_feat(const XT* __restrict__ X, const float* __restrict__ W,
               const float* __restrict__ ASRC, const float* __restrict__ ADST,
               _Float16* __restrict__ Hh, float* __restrict__ AS,
               float* __restrict__ AD, int N) {
    constexpr int LDH = K + 8;
    __shared__ _Float16 Xh[64 * LDH];
    __shared__ _Float16 WT[64 * LDH];
    gemm_mfma_body<K, XT>(X, W, ASRC, ADST, Hh, AS, AD, N, blockIdx.x, Xh, WT);
}

// ---------------------------------------------------------------------------
// Single-node full-wave aggregation (deg > 32 fallback, incl. deg > 64).
// csr entries are plain (masked) source indices; works for LDS or global ptr.
// ---------------------------------------------------------------------------
template <typename OT>
__device__ __forceinline__
void agg_one_node(const _Float16* __restrict__ Hh, const float* __restrict__ AS,
                  const float* __restrict__ AD, const int* __restrict__ csr_src,
                  const float* __restrict__ bias, OT* __restrict__ OUT,
                  int n, int base, int end, int lane, int relu) {
    const int cnt = end - base;
    const float adn = AD[n];

    if (cnt > 64) {   // rare scalar 2-pass path
        float m = -INFINITY;
        for (int c0 = base; c0 < end; c0 += 64) {
            int c = min(64, end - c0);
            float e = -INFINITY;
            if (lane < c) {
                int sr = csr_src[c0 + lane];
                float t = AS[sr] + adn;
                e = t > 0.f ? t : 0.2f * t;
            }
#pragma unroll
            for (int off = 32; off > 0; off >>= 1) e = fmaxf(e, __shfl_xor(e, off, 64));
            m = fmaxf(m, e);
        }
        float s = 0.f, acc = 0.f;
        for (int c0 = base; c0 < end; c0 += 64) {
            int c = min(64, end - c0);
            int srcl = 0;
            float p = 0.f;
            if (lane < c) {
                srcl = csr_src[c0 + lane];
                float t = AS[srcl] + adn;
                t = t > 0.f ? t : 0.2f * t;
                p = __expf(t - m);
            }
            float cs = p;
#pragma unroll
            for (int off = 32; off > 0; off >>= 1) cs += __shfl_xor(cs, off, 64);
            s += cs;
            for (int j = 0; j < c; ++j)
                acc += __shfl(p, j, 64) *
                       (float)Hh[(size_t)__shfl(srcl, j, 64) * 64 + lane];
        }
        float o = acc * (1.f / (s + 1e-16f)) + bias[lane];
        if (relu) o = fmaxf(o, 0.f);
        OUT[(size_t)n * 64 + lane] = (OT)o;
        return;
    }

    // deg <= 64 full-wave path
    int srcl = 0;
    float el = 0.f;
    if (lane < cnt) {
        srcl = csr_src[base + lane];
        float e = AS[srcl] + adn;
        el = e > 0.f ? e : 0.2f * e;
    }
    float p = (lane < cnt) ? __expf(el) : 0.f;
    float s = p;
#pragma unroll
    for (int off = 32; off > 0; off >>= 1) s += __shfl_xor(s, off, 64);
    const float inv = 1.f / (s + 1e-16f);

    const int eg = lane >> 3;
    const int c8 = (lane & 7) * 8;

    float acc[8], acc2[8];
#pragma unroll
    for (int t = 0; t < 8; ++t) { acc[t] = 0.f; acc2[t] = 0.f; }

    int j = 0;
    for (; j + 16 <= cnt; j += 16) {
        int iA = j + eg, iB = j + 8 + eg;
        int sA = __shfl(srcl, iA, 64), sB = __shfl(srcl, iB, 64);
        float aA = __shfl(p, iA, 64),  aB = __shfl(p, iB, 64);
        half8 hA = *(const half8*)(Hh + (size_t)sA * 64 + c8);
        half8 hB = *(const half8*)(Hh + (size_t)sB * 64 + c8);
#pragma unroll
        for (int t = 0; t < 8; ++t) {
            acc[t]  += aA * (float)hA[t];
            acc2[t] += aB * (float)hB[t];
        }
    }
    for (; j < cnt; j += 8) {
        int iA = j + eg;
        int sA = __shfl(srcl, iA, 64);
        float aA = __shfl(p, iA, 64);
        half8 hA = *(const half8*)(Hh + (size_t)sA * 64 + c8);
#pragma unroll
        for (int t = 0; t < 8; ++t) acc[t] += aA * (float)hA[t];
    }
#pragma unroll
    for (int t = 0; t < 8; ++t) acc[t] += acc2[t];
#pragma unroll
    for (int off = 8; off <= 32; off <<= 1)
#pragma unroll
        for (int t = 0; t < 8; ++t) acc[t] += __shfl_xor(acc[t], off, 64);

    if (lane < 8) {
        float4 b0 = *(const float4*)(bias + c8);
        float4 b1 = *(const float4*)(bias + c8 + 4);
        float o[8];
        o[0] = acc[0] * inv + b0.x; o[1] = acc[1] * inv + b0.y;
        o[2] = acc[2] * inv + b0.z; o[3] = acc[3] * inv + b0.w;
        o[4] = acc[4] * inv + b1.x; o[5] = acc[5] * inv + b1.y;
        o[6] = acc[6] * inv + b1.z; o[7] = acc[7] * inv + b1.w;
        if (relu) {
#pragma unroll
            for (int t = 0; t < 8; ++t) o[t] = fmaxf(o[t], 0.f);
        }
        if constexpr (sizeof(OT) == 2) {
            half8 hv;
#pragma unroll
            for (int t = 0; t < 8; ++t) hv[t] = (_Float16)o[t];
            *(half8*)((_Float16*)OUT + (size_t)n * 64 + c8) = hv;
        } else {
            *(float4*)((float*)OUT + (size_t)n * 64 + c8) =
                make_float4(o[0], o[1], o[2], o[3]);
            *(float4*)((float*)OUT + (size_t)n * 64 + c8 + 4) =
                make_float4(o[4], o[5], o[6], o[7]);
        }
    }
}

// ---------------------------------------------------------------------------
// Paired (2 nodes per wave) softmax+aggregate. base/end supplied per-lane by
// the caller (lane<32: node A's, lane>=32: node B's). deg<=32 fast path.
// ---------------------------------------------------------------------------
template <typename OT>
__device__ __forceinline__
void agg_pair_core(const _Float16* __restrict__ Hh, const float* __restrict__ AS,
                   const float* __restrict__ AD, const int* __restrict__ csr,
                   const float* __restrict__ bias, OT* __restrict__ OUT,
                   int n, int N, int relu, int lane, int base, int end) {
    const int l32 = lane & 31;
    const int cnt = end - base;

    if (!__all(cnt <= 32)) {
        int baseA = __shfl(base, 0, 64),  endA = __shfl(end, 0, 64);
        int baseB = __shfl(base, 32, 64), endB = __shfl(end, 32, 64);
        int nA = __shfl(n, 0, 64), nB = __shfl(n, 32, 64);
        if (nA < N) agg_one_node<OT>(Hh, AS, AD, csr, bias, OUT, nA, baseA, endA, lane, relu);
        if (nB < N) agg_one_node<OT>(Hh, AS, AD, csr, bias, OUT, nB, baseB, endB, lane, relu);
        return;
    }

    const float adn = (n < N) ? AD[n] : 0.f;
    int srcl = 0;
    float p = 0.f;
    if (l32 < cnt) {
        srcl = csr[base + l32];
        float e = AS[srcl] + adn;
        e = e > 0.f ? e : 0.2f * e;
        p = __expf(e);
    }
    float s = p;
#pragma unroll
    for (int off = 16; off > 0; off >>= 1) s += __shfl_xor(s, off, 64);
    const float inv = 1.f / (s + 1e-16f);

    const int eg = l32 >> 3;
    const int c8 = (l32 & 7) * 8;

    float acc[8], acc2[8];
#pragma unroll
    for (int t = 0; t < 8; ++t) { acc[t] = 0.f; acc2[t] = 0.f; }

    int j = 0;
    for (; j + 8 <= cnt; j += 8) {
        int iA = j + eg, iB = j + 4 + eg;
        int sA = __shfl(srcl, iA, 32), sB = __shfl(srcl, iB, 32);
        float aA = __shfl(p, iA, 32),  aB = __shfl(p, iB, 32);
        half8 hA = *(const half8*)(Hh + (size_t)sA * 64 + c8);
        half8 hB = *(const half8*)(Hh + (size_t)sB * 64 + c8);
#pragma unroll
        for (int t = 0; t < 8; ++t) {
            acc[t]  += aA * (float)hA[t];
            acc2[t] += aB * (float)hB[t];
        }
    }
    for (; j < cnt; j += 4) {
        int iA = j + eg;
        int sA = __shfl(srcl, iA, 32);
        float aA = __shfl(p, iA, 32);
        half8 hA = *(const half8*)(Hh + (size_t)sA * 64 + c8);
#pragma unroll
        for (int t = 0; t < 8; ++t) acc[t] += aA * (float)hA[t];
    }
#pragma unroll
    for (int t = 0; t < 8; ++t) acc[t] += acc2[t];
#pragma unroll
    for (int t = 0; t < 8; ++t) acc[t] += __shfl_xor(acc[t], 8, 64);
#pragma unroll
    for (int t = 0; t < 8; ++t) acc[t] += __shfl_xor(acc[t], 16, 64);

    if (l32 < 8 && n < N) {
        float4 b0 = *(const float4*)(bias + c8);
        float4 b1 = *(const float4*)(bias + c8 + 4);
        float o[8];
        o[0] = acc[0] * inv + b0.x; o[1] = acc[1] * inv + b0.y;
        o[2] = acc[2] * inv + b0.z; o[3] = acc[3] * inv + b0.w;
        o[4] = acc[4] * inv + b1.x; o[5] = acc[5] * inv + b1.y;
        o[6] = acc[6] * inv + b1.z; o[7] = acc[7] * inv + b1.w;
        if (relu) {
#pragma unroll
            for (int t = 0; t < 8; ++t) o[t] = fmaxf(o[t], 0.f);
        }
        if constexpr (sizeof(OT) == 2) {
            half8 hv;
#pragma unroll
            for (int t = 0; t < 8; ++t) hv[t] = (_Float16)o[t];
            *(half8*)((_Float16*)OUT + (size_t)n * 64 + c8) = hv;
        } else {
            *(float4*)((float*)OUT + (size_t)n * 64 + c8) =
                make_float4(o[0], o[1], o[2], o[3]);
            *(float4*)((float*)OUT + (size_t)n * 64 + c8 + 4) =
                make_float4(o[4], o[5], o[6], o[7]);
        }
    }
}

// ---------------------------------------------------------------------------
// Dispatch 2 (new): per-bucket CSR-less sort + layer-1 aggregate.
// Gather bucket's segments from K1's private slabs -> LDS; node-hist/scan/
// scatter in LDS; publish bucket CSR (ebuck2 slab + rp2 row table,
// block-private coalesced writes) for the layer-2 aggregate; then aggregate
// layer-1 for this bucket's 128 nodes from LDS (8 waves x 8 serial pairs —
// R6 measured this serialization ~neutral). Replaces colscan + to_csr + agg1.
// q-loop unroll 1 (R4/R5 lesson: force-unrolled agg calls blow up the build).
// ---------------------------------------------------------------------------
__global__ __launch_bounds__(512)
void bucket_agg1(const int* __restrict__ ebuck, const int* __restrict__ rows,
                 int nblk, int N,
                 const _Float16* __restrict__ Hh, const float* __restrict__ AS1,
                 const float* __restrict__ AD1, const float* __restrict__ b1,
                 _Float16* __restrict__ R1h,
                 int* __restrict__ ebuck2, int* __restrict__ rp2) {
    __shared__ int eL[CAP];
    __shared__ int eS[CAP];
    __shared__ int hist[NPB];
    __shared__ int cur[NPB];
    __shared__ int rowr[RPS];
    __shared__ int wsums[8];
    __shared__ int cursor;
    const int b = blockIdx.x, tid = threadIdx.x;

    if (tid < NPB) hist[tid] = 0;
    if (tid == 0) cursor = 0;
    __syncthreads();

    // stage segments (order nondeterministic — within-node summation order is
    // nondeterministic anyway via the LDS scatter; tolerance absorbs it)
    for (int blk = tid; blk < nblk; blk += 512) {
        int r0 = rows[blk * RSTR + b];
        int r1 = rows[blk * RSTR + b + 1];
        int len = r1 - r0;
        if (len > 0) {
            int ofs = atomicAdd(&cursor, len);
            for (int i = 0; i < len; ++i)
                if (ofs + i < CAP) eL[ofs + i] = ebuck[blk * EPB + r0 + i];
        }
    }
    __syncthreads();
    const int btot = min(cursor, CAP);

    for (int e = tid; e < btot; e += 512)
        atomicAdd(&hist[((unsigned)eL[e]) >> PACK_SH], 1);
    __syncthreads();
    int v = (tid < NPB) ? hist[tid] : 0;
    int tot;
    int excl = block_scan_tot<8>(v, tid, wsums, &tot);
    if (tid < NPB) { cur[tid] = excl; rowr[tid] = excl; }
    if (tid == 0) rowr[NPB] = btot;
    __syncthreads();
    for (int e = tid; e < btot; e += 512) {
        int pv = eL[e];
        int p = atomicAdd(&cur[((unsigned)pv) >> PACK_SH], 1);
        eS[p] = pv & SRCMASK;
    }
    __syncthreads();

    // publish bucket CSR for layer-2 (block-private, coalesced)
    for (int i = tid; i < btot; i += 512)
        ebuck2[(size_t)b * CAP + i] = eS[i];
    for (int j = tid; j < RPS; j += 512)
        rp2[b * RPS + j] = rowr[j];

    // aggregate layer-1: 8 waves x 8 pairs = 128 nodes
    const int lane = tid & 63, w = tid >> 6;
    const int half = lane >> 5;
#pragma unroll 1
    for (int q = 0; q < 8; ++q) {
        int nloc = w * 16 + q * 2 + half;
        int n = (b << BSH) + nloc;
        int base = rowr[nloc], end = rowr[nloc + 1];  // n>=N => hist 0 => cnt 0
        agg_pair_core<_Float16>(Hh, AS1, AD1, (const int*)eS, b1, R1h,
                                n, N, 1, lane, base, end);
    }
}

// ---------------------------------------------------------------------------
// Dispatch 4: standalone paired aggregate (layer 2, fp32 out), indexing the
// bucket-slab CSR (25000 waves — max latency hiding).
// ---------------------------------------------------------------------------
__global__ __launch_bounds__(256)
void gat_aggregate2(const _Float16* __restrict__ Hh, const float* __restrict__ AS,
                    const float* __restrict__ AD, const int* __restrict__ ebuck2,
                    const int* __restrict__ rp2, const float* __restrict__ bias,
                    float* __restrict__ OUT, int N) {
    const int lane = threadIdx.x & 63;
    const int half = lane >> 5;
    const int pair0 = blockIdx.x * 8 + (threadIdx.x >> 6) * 2;
    if (pair0 >= N) return;
    const int n = pair0 + half;
    int base = 0, end = 0;
    if (n < N) {
        int b = n >> BSH, j = n & (NPB - 1);
        base = b * CAP + rp2[b * RPS + j];
        end  = b * CAP + rp2[b * RPS + j + 1];
    }
    agg_pair_core<float>(Hh, AS, AD, ebuck2, bias, OUT, n, N, 0, lane, base, end);
}

// ---------------------------------------------------------------------------
extern "C" void kernel_launch(void* const* d_in, const int* in_sizes, int n_in,
                              void* d_out, int out_size, void* d_ws, size_t ws_size,
                              hipStream_t stream) {
    const float* x    = (const float*)d_in[0];
    const int*   ei   = (const int*)d_in[1];
    const float* W1   = (const float*)d_in[2];
    const float* as1w = (const float*)d_in[3];
    const float* ad1w = (const float*)d_in[4];
    const float* b1   = (const float*)d_in[5];
    const float* W2   = (const float*)d_in[6];
    const float* as2w = (const float*)d_in[7];
    const float* ad2w = (const float*)d_in[8];
    const float* b2   = (const float*)d_in[9];
    float* out = (float*)d_out;

    const int N = in_sizes[0] / FIN;   // 50000
    const int E = in_sizes[1] / 2;     // 800000
    const int* esrc = ei;
    const int* edst = ei + E;

    const int nbuck = (N + NPB - 1) >> BSH;      // 391
    const int nblk  = (E + EPB - 1) / EPB;       // 391

    char* wp8 = (char*)d_ws;
    _Float16* Hh  = (_Float16*)wp8;  wp8 += (size_t)N * 64 * 2;   // layer-1 h
    _Float16* R1h = (_Float16*)wp8;  wp8 += (size_t)N * 64 * 2;   // agg1 out
    _Float16* H2h = (_Float16*)wp8;  wp8 += (size_t)N * 64 * 2;   // layer-2 h
    float* AS1 = (float*)wp8;        wp8 += (size_t)N * 4;
    float* AD1 = (float*)wp8;        wp8 += (size_t)N * 4;
    float* AS2 = (float*)wp8;        wp8 += (size_t)N * 4;
    float* AD2 = (float*)wp8;        wp8 += (size_t)N * 4;
    int* ebuck  = (int*)wp8;         wp8 += (size_t)nblk * EPB * 4;
    int* rows   = (int*)wp8;         wp8 += (size_t)nblk * RSTR * 4;
    int* ebuck2 = (int*)wp8;         wp8 += (size_t)nbuck * CAP * 4;
    int* rp2    = (int*)wp8;         wp8 += (size_t)nbuck * RPS * 4;

    const int nbG = (N + 63) / 64;               // 782
    const int nbAgg = (N + 7) / 8;               // 6250

    // 1) fused: LDS bucket-sort (391 blocks) + MFMA gemm layer-1
    hipLaunchKernelGGL(gemm1_and_sort, dim3(nblk + nbG), dim3(256), 0, stream,
                       x, W1, as1w, ad1w, Hh, AS1, AD1, N,
                       esrc, edst, E, nblk, nbuck, rows, ebuck);
    // 2) per-bucket: gather -> LDS node-sort -> publish bucket CSR -> agg1
    hipLaunchKernelGGL(bucket_agg1, dim3(nbuck), dim3(512), 0, stream,
                       ebuck, rows, nblk, N, Hh, AS1, AD1, b1, R1h,
                       ebuck2, rp2);
    // 3) MFMA gemm layer-2 (fp16 in)
    hipLaunchKernelGGL((gemm_feat<64, _Float16>), dim3(nbG), dim3(256), 0, stream,
                       R1h, W2, as2w, ad2w, H2h, AS2, AD2, N);
    // 4) aggregate layer-2 (fp32 out, bucket-slab CSR)
    hipLaunchKernelGGL(gat_aggregate2, dim3(nbAgg), dim3(256), 0, stream,
                       H2h, AS2, AD2, ebuck2, rp2, b2, out, N);
}

// Round 8
// 159.135 us; speedup vs baseline: 1.1177x; 1.0226x over previous
//
#include <hip/hip_runtime.h>
#include <cstddef>

constexpr int FIN = 128;
constexpr int EPB = 2048;   // edges per block in sort pass (391 blocks)
constexpr int BSH = 7;      // bucket shift: 128 nodes per bucket
constexpr int NPB = 128;    // nodes per bucket
constexpr int PACK_SH = 25; // pack: (dst_local << 25) | src (src < 2^25)
constexpr int SRCMASK = (1 << PACK_SH) - 1;
constexpr int RSTR = 512;   // rows matrix stride (nbuck+1 <= 512)
constexpr int CAP = 4608;   // per-bucket edge cap (mean 2048, sd ~45)
constexpr int RPS = NPB + 1; // per-bucket row-table stride (129)

typedef _Float16 half4 __attribute__((ext_vector_type(4)));
typedef _Float16 half8 __attribute__((ext_vector_type(8)));
typedef float floatx4 __attribute__((ext_vector_type(4)));

// ---------------------------------------------------------------------------
// Block-wide exclusive scan over NW waves (NW*64 threads); returns total.
// ---------------------------------------------------------------------------
template <int NW>
__device__ __forceinline__ int block_scan_tot(int v, int tid, int* wsums,
                                              int* tot) {
    int lane = tid & 63, w = tid >> 6;
    int x = v;
#pragma unroll
    for (int off = 1; off < 64; off <<= 1) {
        int y = __shfl_up(x, off, 64);
        if (lane >= off) x += y;
    }
    if (lane == 63) wsums[w] = x;
    __syncthreads();
    int add = 0, t = 0;
#pragma unroll
    for (int i = 0; i < NW; ++i) {
        add += (i < w) ? wsums[i] : 0;
        t += wsums[i];
    }
    *tot = t;
    return x + add - v;
}

// ---------------------------------------------------------------------------
// MFMA GEMM core (256 threads): W-stage + sync + MFMA + AS/AD epilogue + Hh.
// ---------------------------------------------------------------------------
template <int K>
__device__ __forceinline__
void gemm_core(const float* __restrict__ W, const float* __restrict__ ASRC,
               const float* __restrict__ ADST, _Float16* __restrict__ Hh,
               float* __restrict__ AS, float* __restrict__ AD, int N, int nb,
               _Float16* Xh, _Float16* WT) {
    constexpr int LDH = K + 8;
    const int tid = threadIdx.x;
    for (int i = tid; i < 64 * (K / 4); i += 256) {
        int n = i & 63, kg = i >> 6;
        half4 h;
#pragma unroll
        for (int j = 0; j < 4; ++j)
            h[j] = (_Float16)W[(4 * kg + j) * 64 + n];
        *(half4*)(WT + n * LDH + 4 * kg) = h;
    }
    __syncthreads();

    const int l = tid & 63;
    const int r0 = (tid >> 6) * 16;
    const int n16 = l & 15, quad = l >> 4;

    floatx4 acc[4];
#pragma unroll
    for (int nt = 0; nt < 4; ++nt) acc[nt] = (floatx4){0.f, 0.f, 0.f, 0.f};

#pragma unroll
    for (int k0 = 0; k0 < K; k0 += 32) {
        half8 a = *(const half8*)(Xh + (r0 + n16) * LDH + k0 + quad * 8);
#pragma unroll
        for (int nt = 0; nt < 4; ++nt) {
            half8 b = *(const half8*)(WT + (nt * 16 + n16) * LDH + k0 + quad * 8);
            acc[nt] = __builtin_amdgcn_mfma_f32_16x16x32_f16(a, b, acc[nt], 0, 0, 0);
        }
    }

    float pa[4] = {0.f, 0.f, 0.f, 0.f}, pd[4] = {0.f, 0.f, 0.f, 0.f};
#pragma unroll
    for (int nt = 0; nt < 4; ++nt) {
        float as_v = ASRC[nt * 16 + n16], ad_v = ADST[nt * 16 + n16];
#pragma unroll
        for (int reg = 0; reg < 4; ++reg) {
            pa[reg] += acc[nt][reg] * as_v;
            pd[reg] += acc[nt][reg] * ad_v;
        }
    }
#pragma unroll
    for (int off = 1; off < 16; off <<= 1) {
#pragma unroll
        for (int reg = 0; reg < 4; ++reg) {
            pa[reg] += __shfl_xor(pa[reg], off, 64);
            pd[reg] += __shfl_xor(pd[reg], off, 64);
        }
    }
    if (n16 == 0) {
#pragma unroll
        for (int reg = 0; reg < 4; ++reg) {
            int row = nb + r0 + quad * 4 + reg;
            if (row < N) { AS[row] = pa[reg]; AD[row] = pd[reg]; }
        }
    }

#pragma unroll
    for (int nt = 0; nt < 4; ++nt)
#pragma unroll
        for (int reg = 0; reg < 4; ++reg)
            Xh[(r0 + quad * 4 + reg) * LDH + nt * 16 + n16] = (_Float16)acc[nt][reg];
    {
        int r = r0 + (l >> 2);
        int o = (l & 3) * 16;
        if (nb + r < N) {
            half8 v0 = *(const half8*)(Xh + r * LDH + o);
            half8 v1 = *(const half8*)(Xh + r * LDH + o + 8);
            *(half8*)(Hh + (size_t)(nb + r) * 64 + o) = v0;
            *(half8*)(Hh + (size_t)(nb + r) * 64 + o + 8) = v1;
        }
    }
}

// gemm body with global X staging (layer 1)
template <int K, typename XT>
__device__ __forceinline__
void gemm_mfma_body(const XT* __restrict__ X, const float* __restrict__ W,
                    const float* __restrict__ ASRC, const float* __restrict__ ADST,
                    _Float16* __restrict__ Hh, float* __restrict__ AS,
                    float* __restrict__ AD, int N, int blk,
                    _Float16* Xh, _Float16* WT) {
    constexpr int LDH = K + 8;
    const int tid = threadIdx.x;
    const int nb = blk * 64;
    if constexpr (sizeof(XT) == 4) {
        constexpr int QPR = K / 4;
        for (int i = tid; i < 64 * QPR; i += 256) {
            int r = i / QPR, q = i % QPR;
            float4 v = make_float4(0.f, 0.f, 0.f, 0.f);
            if (nb + r < N) v = *(const float4*)(X + (size_t)(nb + r) * K + 4 * q);
            half4 h; h[0] = (_Float16)v.x; h[1] = (_Float16)v.y;
            h[2] = (_Float16)v.z; h[3] = (_Float16)v.w;
            *(half4*)(Xh + r * LDH + 4 * q) = h;
        }
    } else {
        constexpr int OPR = K / 8;
        for (int i = tid; i < 64 * OPR; i += 256) {
            int r = i / OPR, o = i % OPR;
            half8 v = {};
            if (nb + r < N) v = *(const half8*)(X + (size_t)(nb + r) * K + 8 * o);
            *(half8*)(Xh + r * LDH + 8 * o) = v;
        }
    }
    gemm_core<K>(W, ASRC, ADST, Hh, AS, AD, N, nb, Xh, WT);
}

// ---------------------------------------------------------------------------
// Dispatch 1: blocks [0, nblk) LDS-bucket-sort their 2048 edges into a
// block-PRIVATE ebuck slab (R2 lesson: scattered 4B cross-XCD writes are
// 16x amplified) and emit per-(blk,bucket) offsets (rows). Rest: gemm layer-1.
// ---------------------------------------------------------------------------
__global__ __launch_bounds__(256)
void gemm1_and_sort(const float* __restrict__ X, const float* __restrict__ W,
                    const float* __restrict__ ASRC, const float* __restrict__ ADST,
                    _Float16* __restrict__ Hh, float* __restrict__ AS,
                    float* __restrict__ AD, int N,
                    const int* __restrict__ src, const int* __restrict__ dst,
                    int E, int nblk, int nbuck,
                    int* __restrict__ rows, int* __restrict__ ebuck) {
    constexpr int K = FIN, LDH = K + 8;
    __shared__ _Float16 Xh[64 * LDH];
    __shared__ _Float16 WT[64 * LDH];
    __shared__ int wsums[4];

    const int tid = threadIdx.x;
    if ((int)blockIdx.x < nblk) {
        int* sorted = (int*)Xh;          // up to 2048 ints
        int* hist   = (int*)WT;          // 512 ints
        int* cur    = hist + 512;        // 512 ints
        for (int i = tid; i < nbuck; i += 256) hist[i] = 0;
        __syncthreads();

        const int e0 = blockIdx.x * EPB;
        const int e1 = min(e0 + EPB, E);
        const int cnt = e1 - e0;

        int pay[8], bk[8];
#pragma unroll
        for (int k = 0; k < 8; ++k) {
            int e = e0 + tid + k * 256;
            bk[k] = -1; pay[k] = 0;
            if (e < e1) {
                int d = dst[e];
                bk[k] = d >> BSH;
                pay[k] = ((d & (NPB - 1)) << PACK_SH) | src[e];
                atomicAdd(&hist[bk[k]], 1);
            }
        }
        __syncthreads();

        int i0 = 2 * tid, i1 = 2 * tid + 1;
        int v0 = (i0 < nbuck) ? hist[i0] : 0;
        int v1 = (i1 < nbuck) ? hist[i1] : 0;
        int tot;
        int ex = block_scan_tot<4>(v0 + v1, tid, wsums, &tot);
        if (i0 < nbuck) {
            cur[i0] = ex;
            rows[blockIdx.x * RSTR + i0] = ex;
        }
        if (i1 < nbuck) {
            cur[i1] = ex + v0;
            rows[blockIdx.x * RSTR + i1] = ex + v0;
        }
        if (tid == 0) rows[blockIdx.x * RSTR + nbuck] = cnt;
        __syncthreads();

#pragma unroll
        for (int k = 0; k < 8; ++k) {
            if (bk[k] >= 0) {
                int p = atomicAdd(&cur[bk[k]], 1);
                sorted[p] = pay[k];
            }
        }
        __syncthreads();
        for (int i = tid; i < cnt; i += 256)
            ebuck[blockIdx.x * EPB + i] = sorted[i];
        return;
    }
    gemm_mfma_body<K, float>(X, W, ASRC, ADST, Hh, AS, AD, N,
                             blockIdx.x - nblk, Xh, WT);
}

// ---------------------------------------------------------------------------
// Single-node full-wave aggregation (deg > 32 fallback, incl. deg > 64).
// LDSOUT: write node's 64-ch fp16 row to ldsX[(n&127)*72 + c].
// ---------------------------------------------------------------------------
template <bool LDSOUT, typename OT>
__device__ __forceinline__
void agg_one_node(const _Float16* __restrict__ Hh, const float* __restrict__ AS,
                  const float* __restrict__ AD, const int* __restrict__ csr_src,
                  const float* __restrict__ bias, OT* __restrict__ OUT,
                  _Float16* ldsX, int n, int base, int end, int lane, int relu) {
    const int cnt = end - base;
    const float adn = AD[n];

    if (cnt > 64) {   // rare scalar 2-pass path
        float m = -INFINITY;
        for (int c0 = base; c0 < end; c0 += 64) {
            int c = min(64, end - c0);
            float e = -INFINITY;
            if (lane < c) {
                int sr = csr_src[c0 + lane];
                float t = AS[sr] + adn;
                e = t > 0.f ? t : 0.2f * t;
            }
#pragma unroll
            for (int off = 32; off > 0; off >>= 1) e = fmaxf(e, __shfl_xor(e, off, 64));
            m = fmaxf(m, e);
        }
        float s = 0.f, acc = 0.f;
        for (int c0 = base; c0 < end; c0 += 64) {
            int c = min(64, end - c0);
            int srcl = 0;
            float p = 0.f;
            if (lane < c) {
                srcl = csr_src[c0 + lane];
                float t = AS[srcl] + adn;
                t = t > 0.f ? t : 0.2f * t;
                p = __expf(t - m);
            }
            float cs = p;
#pragma unroll
            for (int off = 32; off > 0; off >>= 1) cs += __shfl_xor(cs, off, 64);
            s += cs;
            for (int j = 0; j < c; ++j)
                acc += __shfl(p, j, 64) *
                       (float)Hh[(size_t)__shfl(srcl, j, 64) * 64 + lane];
        }
        float o = acc * (1.f / (s + 1e-16f)) + bias[lane];
        if (relu) o = fmaxf(o, 0.f);
        if constexpr (LDSOUT) ldsX[(n & (NPB - 1)) * 72 + lane] = (_Float16)o;
        else OUT[(size_t)n * 64 + lane] = (OT)o;
        return;
    }

    // deg <= 64 full-wave path
    int srcl = 0;
    float el = 0.f;
    if (lane < cnt) {
        srcl = csr_src[base + lane];
        float e = AS[srcl] + adn;
        el = e > 0.f ? e : 0.2f * e;
    }
    float p = (lane < cnt) ? __expf(el) : 0.f;
    float s = p;
#pragma unroll
    for (int off = 32; off > 0; off >>= 1) s += __shfl_xor(s, off, 64);
    const float inv = 1.f / (s + 1e-16f);

    const int eg = lane >> 3;
    const int c8 = (lane & 7) * 8;

    float acc[8], acc2[8];
#pragma unroll
    for (int t = 0; t < 8; ++t) { acc[t] = 0.f; acc2[t] = 0.f; }

    int j = 0;
    for (; j + 16 <= cnt; j += 16) {
        int iA = j + eg, iB = j + 8 + eg;
        int sA = __shfl(srcl, iA, 64), sB = __shfl(srcl, iB, 64);
        float aA = __shfl(p, iA, 64),  aB = __shfl(p, iB, 64);
        half8 hA = *(const half8*)(Hh + (size_t)sA * 64 + c8);
        half8 hB = *(const half8*)(Hh + (size_t)sB * 64 + c8);
#pragma unroll
        for (int t = 0; t < 8; ++t) {
            acc[t]  += aA * (float)hA[t];
            acc2[t] += aB * (float)hB[t];
        }
    }
    for (; j < cnt; j += 8) {
        int iA = j + eg;
        int sA = __shfl(srcl, iA, 64);
        float aA = __shfl(p, iA, 64);
        half8 hA = *(const half8*)(Hh + (size_t)sA * 64 + c8);
#pragma unroll
        for (int t = 0; t < 8; ++t) acc[t] += aA * (float)hA[t];
    }
#pragma unroll
    for (int t = 0; t < 8; ++t) acc[t] += acc2[t];
#pragma unroll
    for (int off = 8; off <= 32; off <<= 1)
#pragma unroll
        for (int t = 0; t < 8; ++t) acc[t] += __shfl_xor(acc[t], off, 64);

    if (lane < 8) {
        float4 b0 = *(const float4*)(bias + c8);
        float4 b1 = *(const float4*)(bias + c8 + 4);
        float o[8];
        o[0] = acc[0] * inv + b0.x; o[1] = acc[1] * inv + b0.y;
        o[2] = acc[2] * inv + b0.z; o[3] = acc[3] * inv + b0.w;
        o[4] = acc[4] * inv + b1.x; o[5] = acc[5] * inv + b1.y;
        o[6] = acc[6] * inv + b1.z; o[7] = acc[7] * inv + b1.w;
        if (relu) {
#pragma unroll
            for (int t = 0; t < 8; ++t) o[t] = fmaxf(o[t], 0.f);
        }
        if constexpr (LDSOUT) {
            half8 hv;
#pragma unroll
            for (int t = 0; t < 8; ++t) hv[t] = (_Float16)o[t];
            *(half8*)(ldsX + (n & (NPB - 1)) * 72 + c8) = hv;
        } else if constexpr (sizeof(OT) == 2) {
            half8 hv;
#pragma unroll
            for (int t = 0; t < 8; ++t) hv[t] = (_Float16)o[t];
            *(half8*)((_Float16*)OUT + (size_t)n * 64 + c8) = hv;
        } else {
            *(float4*)((float*)OUT + (size_t)n * 64 + c8) =
                make_float4(o[0], o[1], o[2], o[3]);
            *(float4*)((float*)OUT + (size_t)n * 64 + c8 + 4) =
                make_float4(o[4], o[5], o[6], o[7]);
        }
    }
}

// ---------------------------------------------------------------------------
// Paired (2 nodes per wave) softmax+aggregate; base/end supplied per-lane.
// LDSOUT: output rows to ldsX[(n&127)*72].
// ---------------------------------------------------------------------------
template <bool LDSOUT, typename OT>
__device__ __forceinline__
void agg_pair_core(const _Float16* __restrict__ Hh, const float* __restrict__ AS,
                   const float* __restrict__ AD, const int* __restrict__ csr,
                   const float* __restrict__ bias, OT* __restrict__ OUT,
                   _Float16* ldsX, int n, int N, int relu, int lane,
                   int base, int end) {
    const int l32 = lane & 31;
    const int cnt = end - base;

    if (!__all(cnt <= 32)) {
        int baseA = __shfl(base, 0, 64),  endA = __shfl(end, 0, 64);
        int baseB = __shfl(base, 32, 64), endB = __shfl(end, 32, 64);
        int nA = __shfl(n, 0, 64), nB = __shfl(n, 32, 64);
        if (nA < N) agg_one_node<LDSOUT, OT>(Hh, AS, AD, csr, bias, OUT, ldsX,
                                             nA, baseA, endA, lane, relu);
        if (nB < N) agg_one_node<LDSOUT, OT>(Hh, AS, AD, csr, bias, OUT, ldsX,
                                             nB, baseB, endB, lane, relu);
        return;
    }

    const float adn = (n < N) ? AD[n] : 0.f;
    int srcl = 0;
    float p = 0.f;
    if (l32 < cnt) {
        srcl = csr[base + l32];
        float e = AS[srcl] + adn;
        e = e > 0.f ? e : 0.2f * e;
        p = __expf(e);
    }
    float s = p;
#pragma unroll
    for (int off = 16; off > 0; off >>= 1) s += __shfl_xor(s, off, 64);
    const float inv = 1.f / (s + 1e-16f);

    const int eg = l32 >> 3;
    const int c8 = (l32 & 7) * 8;

    float acc[8], acc2[8];
#pragma unroll
    for (int t = 0; t < 8; ++t) { acc[t] = 0.f; acc2[t] = 0.f; }

    int j = 0;
    for (; j + 8 <= cnt; j += 8) {
        int iA = j + eg, iB = j + 4 + eg;
        int sA = __shfl(srcl, iA, 32), sB = __shfl(srcl, iB, 32);
        float aA = __shfl(p, iA, 32),  aB = __shfl(p, iB, 32);
        half8 hA = *(const half8*)(Hh + (size_t)sA * 64 + c8);
        half8 hB = *(const half8*)(Hh + (size_t)sB * 64 + c8);
#pragma unroll
        for (int t = 0; t < 8; ++t) {
            acc[t]  += aA * (float)hA[t];
            acc2[t] += aB * (float)hB[t];
        }
    }
    for (; j < cnt; j += 4) {
        int iA = j + eg;
        int sA = __shfl(srcl, iA, 32);
        float aA = __shfl(p, iA, 32);
        half8 hA = *(const half8*)(Hh + (size_t)sA * 64 + c8);
#pragma unroll
        for (int t = 0; t < 8; ++t) acc[t] += aA * (float)hA[t];
    }
#pragma unroll
    for (int t = 0; t < 8; ++t) acc[t] += acc2[t];
#pragma unroll
    for (int t = 0; t < 8; ++t) acc[t] += __shfl_xor(acc[t], 8, 64);
#pragma unroll
    for (int t = 0; t < 8; ++t) acc[t] += __shfl_xor(acc[t], 16, 64);

    if (l32 < 8 && n < N) {
        float4 b0 = *(const float4*)(bias + c8);
        float4 b1 = *(const float4*)(bias + c8 + 4);
        float o[8];
        o[0] = acc[0] * inv + b0.x; o[1] = acc[1] * inv + b0.y;
        o[2] = acc[2] * inv + b0.z; o[3] = acc[3] * inv + b0.w;
        o[4] = acc[4] * inv + b1.x; o[5] = acc[5] * inv + b1.y;
        o[6] = acc[6] * inv + b1.z; o[7] = acc[7] * inv + b1.w;
        if (relu) {
#pragma unroll
            for (int t = 0; t < 8; ++t) o[t] = fmaxf(o[t], 0.f);
        }
        if constexpr (LDSOUT) {
            half8 hv;
#pragma unroll
            for (int t = 0; t < 8; ++t) hv[t] = (_Float16)o[t];
            *(half8*)(ldsX + (n & (NPB - 1)) * 72 + c8) = hv;
        } else if constexpr (sizeof(OT) == 2) {
            half8 hv;
#pragma unroll
            for (int t = 0; t < 8; ++t) hv[t] = (_Float16)o[t];
            *(half8*)((_Float16*)OUT + (size_t)n * 64 + c8) = hv;
        } else {
            *(float4*)((float*)OUT + (size_t)n * 64 + c8) =
                make_float4(o[0], o[1], o[2], o[3]);
            *(float4*)((float*)OUT + (size_t)n * 64 + c8 + 4) =
                make_float4(o[4], o[5], o[6], o[7]);
        }
    }
}

// ---------------------------------------------------------------------------
// Dispatch 2 (R8 fused): per-bucket sort + layer-1 aggregate INTO LDS X-tile
// + layer-2 MFMA gemm (two 64-row tiles: waves 0-3 / 4-7). Eliminates the
// R1h HBM round-trip and the gemm_feat dispatch. Xh reuses eL's LDS (both
// 18432 B; eL dead after node-scatter). q-loop unroll 1 (R4/R5 lesson).
// ---------------------------------------------------------------------------
__global__ __launch_bounds__(512)
void bucket_agg1_gemm2(const int* __restrict__ ebuck, const int* __restrict__ rows,
                       int nblk, int N,
                       const _Float16* __restrict__ Hh, const float* __restrict__ AS1,
                       const float* __restrict__ AD1, const float* __restrict__ b1,
                       const float* __restrict__ W2, const float* __restrict__ as2w,
                       const float* __restrict__ ad2w, _Float16* __restrict__ H2h,
                       float* __restrict__ AS2, float* __restrict__ AD2,
                       int* __restrict__ ebuck2, int* __restrict__ rp2) {
    __shared__ int eLX[CAP];           // phase A: edge staging; phase B: Xh[128][72] fp16
    __shared__ int eS[CAP];
    __shared__ _Float16 WT[64 * 72];   // W2^T, shared by both tiles
    __shared__ int hist[NPB];
    __shared__ int cur[NPB];
    __shared__ int rowr[RPS];
    __shared__ int wsums[8];
    __shared__ int cursor;
    const int b = blockIdx.x, tid = threadIdx.x;

    // stage W2^T early (independent of everything else)
    for (int i = tid; i < 64 * 16; i += 512) {
        int n = i & 63, kg = i >> 6;
        half4 h;
#pragma unroll
        for (int j = 0; j < 4; ++j)
            h[j] = (_Float16)W2[(4 * kg + j) * 64 + n];
        *(half4*)(WT + n * 72 + 4 * kg) = h;
    }
    if (tid < NPB) hist[tid] = 0;
    if (tid == 0) cursor = 0;
    __syncthreads();

    // gather this bucket's segments from K1's private slabs
    for (int blk = tid; blk < nblk; blk += 512) {
        int r0 = rows[blk * RSTR + b];
        int r1 = rows[blk * RSTR + b + 1];
        int len = r1 - r0;
        if (len > 0) {
            int ofs = atomicAdd(&cursor, len);
            for (int i = 0; i < len; ++i)
                if (ofs + i < CAP) eLX[ofs + i] = ebuck[blk * EPB + r0 + i];
        }
    }
    __syncthreads();
    const int btot = min(cursor, CAP);

    for (int e = tid; e < btot; e += 512)
        atomicAdd(&hist[((unsigned)eLX[e]) >> PACK_SH], 1);
    __syncthreads();
    int v = (tid < NPB) ? hist[tid] : 0;
    int tot;
    int excl = block_scan_tot<8>(v, tid, wsums, &tot);
    if (tid < NPB) { cur[tid] = excl; rowr[tid] = excl; }
    if (tid == 0) rowr[NPB] = btot;
    __syncthreads();
    for (int e = tid; e < btot; e += 512) {
        int pv = eLX[e];
        int p = atomicAdd(&cur[((unsigned)pv) >> PACK_SH], 1);
        eS[p] = pv & SRCMASK;
    }
    __syncthreads();                   // eLX (eL role) now dead

    // publish bucket CSR for the layer-2 aggregate (block-private, coalesced)
    for (int i = tid; i < btot; i += 512)
        ebuck2[(size_t)b * CAP + i] = eS[i];
    for (int j = tid; j < RPS; j += 512)
        rp2[b * RPS + j] = rowr[j];

    // zero Xh (covers out-of-range rows of the last bucket)
    _Float16* Xh = (_Float16*)eLX;
    for (int i = tid; i < 128 * 72 / 8; i += 512)
        ((half8*)Xh)[i] = (half8){};
    __syncthreads();

    // layer-1 aggregate: 8 waves x 8 pairs = 128 nodes, output into Xh
    const int lane = tid & 63, w = tid >> 6;
    const int half = lane >> 5;
#pragma unroll 1
    for (int q = 0; q < 8; ++q) {
        int nloc = w * 16 + q * 2 + half;
        int n = (b << BSH) + nloc;
        int base = rowr[nloc], end = rowr[nloc + 1];
        agg_pair_core<true, _Float16>(Hh, AS1, AD1, (const int*)eS, b1,
                                      (_Float16*)nullptr, Xh, n, N, 1, lane,
                                      base, end);
    }
    __syncthreads();                   // all Xh rows written before MFMA

    // layer-2 MFMA: two 64-row tiles (tile = tid>>8), shared WT
    const int tt = tid & 255;
    const int tile = tid >> 8;
    const int nb = (b << BSH) + tile * 64;
    _Float16* Xt = Xh + tile * 64 * 72;

    const int l = tt & 63;
    const int r0 = (tt >> 6) * 16;
    const int n16 = l & 15, quad = l >> 4;

    floatx4 acc[4];
#pragma unroll
    for (int nt = 0; nt < 4; ++nt) acc[nt] = (floatx4){0.f, 0.f, 0.f, 0.f};

#pragma unroll
    for (int k0 = 0; k0 < 64; k0 += 32) {
        half8 a = *(const half8*)(Xt + (r0 + n16) * 72 + k0 + quad * 8);
#pragma unroll
        for (int nt = 0; nt < 4; ++nt) {
            half8 bb = *(const half8*)(WT + (nt * 16 + n16) * 72 + k0 + quad * 8);
            acc[nt] = __builtin_amdgcn_mfma_f32_16x16x32_f16(a, bb, acc[nt], 0, 0, 0);
        }
    }

    float pa[4] = {0.f, 0.f, 0.f, 0.f}, pd[4] = {0.f, 0.f, 0.f, 0.f};
#pragma unroll
    for (int nt = 0; nt < 4; ++nt) {
        float as_v = as2w[nt * 16 + n16], ad_v = ad2w[nt * 16 + n16];
#pragma unroll
        for (int reg = 0; reg < 4; ++reg) {
            pa[reg] += acc[nt][reg] * as_v;
            pd[reg] += acc[nt][reg] * ad_v;
        }
    }
#pragma unroll
    for (int off = 1; off < 16; off <<= 1) {
#pragma unroll
        for (int reg = 0; reg < 4; ++reg) {
            pa[reg] += __shfl_xor(pa[reg], off, 64);
            pd[reg] += __shfl_xor(pd[reg], off, 64);
        }
    }
    if (n16 == 0) {
#pragma unroll
        for (int reg = 0; reg < 4; ++reg) {
            int row = nb + r0 + quad * 4 + reg;
            if (row < N) { AS2[row] = pa[reg]; AD2[row] = pd[reg]; }
        }
    }

#pragma unroll
    for (int nt = 0; nt < 4; ++nt)
#pragma unroll
        for (int reg = 0; reg < 4; ++reg)
            Xt[(r0 + quad * 4 + reg) * 72 + nt * 16 + n16] = (_Float16)acc[nt][reg];
    {
        int r = r0 + (l >> 2);
        int o = (l & 3) * 16;
        if (nb + r < N) {
            half8 v0 = *(const half8*)(Xt + r * 72 + o);
            half8 v1 = *(const half8*)(Xt + r * 72 + o + 8);
            *(half8*)(H2h + (size_t)(nb + r) * 64 + o) = v0;
            *(half8*)(H2h + (size_t)(nb + r) * 64 + o + 8) = v1;
        }
    }
}

// ---------------------------------------------------------------------------
// Dispatch 3: standalone paired aggregate (layer 2, fp32 out), indexing the
// bucket-slab CSR (25000 waves — max latency hiding).
// ---------------------------------------------------------------------------
__global__ __launch_bounds__(256)
void gat_aggregate2(const _Float16* __restrict__ Hh, const float* __restrict__ AS,
                    const float* __restrict__ AD, const int* __restrict__ ebuck2,
                    const int* __restrict__ rp2, const float* __restrict__ bias,
                    float* __restrict__ OUT, int N) {
    const int lane = threadIdx.x & 63;
    const int half = lane >> 5;
    const int pair0 = blockIdx.x * 8 + (threadIdx.x >> 6) * 2;
    if (pair0 >= N) return;
    const int n = pair0 + half;
    int base = 0, end = 0;
    if (n < N) {
        int b = n >> BSH, j = n & (NPB - 1);
        base = b * CAP + rp2[b * RPS + j];
        end  = b * CAP + rp2[b * RPS + j + 1];
    }
    agg_pair_core<false, float>(Hh, AS, AD, ebuck2, bias, OUT,
                                (_Float16*)nullptr, n, N, 0, lane, base, end);
}

// ---------------------------------------------------------------------------
extern "C" void kernel_launch(void* const* d_in, const int* in_sizes, int n_in,
                              void* d_out, int out_size, void* d_ws, size_t ws_size,
                              hipStream_t stream) {
    const float* x    = (const float*)d_in[0];
    const int*   ei   = (const int*)d_in[1];
    const float* W1   = (const float*)d_in[2];
    const float* as1w = (const float*)d_in[3];
    const float* ad1w = (const float*)d_in[4];
    const float* b1   = (const float*)d_in[5];
    const float* W2   = (const float*)d_in[6];
    const float* as2w = (const float*)d_in[7];
    const float* ad2w = (const float*)d_in[8];
    const float* b2   = (const float*)d_in[9];
    float* out = (float*)d_out;

    const int N = in_sizes[0] / FIN;   // 50000
    const int E = in_sizes[1] / 2;     // 800000
    const int* esrc = ei;
    const int* edst = ei + E;

    const int nbuck = (N + NPB - 1) >> BSH;      // 391
    const int nblk  = (E + EPB - 1) / EPB;       // 391

    char* wp8 = (char*)d_ws;
    _Float16* Hh  = (_Float16*)wp8;  wp8 += (size_t)N * 64 * 2;   // layer-1 h
    _Float16* H2h = (_Float16*)wp8;  wp8 += (size_t)N * 64 * 2;   // layer-2 h
    float* AS1 = (float*)wp8;        wp8 += (size_t)N * 4;
    float* AD1 = (float*)wp8;        wp8 += (size_t)N * 4;
    float* AS2 = (float*)wp8;        wp8 += (size_t)N * 4;
    float* AD2 = (float*)wp8;        wp8 += (size_t)N * 4;
    int* ebuck  = (int*)wp8;         wp8 += (size_t)nblk * EPB * 4;
    int* rows   = (int*)wp8;         wp8 += (size_t)nblk * RSTR * 4;
    int* ebuck2 = (int*)wp8;         wp8 += (size_t)nbuck * CAP * 4;
    int* rp2    = (int*)wp8;         wp8 += (size_t)nbuck * RPS * 4;

    const int nbG = (N + 63) / 64;               // 782
    const int nbAgg = (N + 7) / 8;               // 6250

    // 1) fused: LDS bucket-sort (391 blocks) + MFMA gemm layer-1
    hipLaunchKernelGGL(gemm1_and_sort, dim3(nblk + nbG), dim3(256), 0, stream,
                       x, W1, as1w, ad1w, Hh, AS1, AD1, N,
                       esrc, edst, E, nblk, nbuck, rows, ebuck);
    // 2) per-bucket: sort -> agg1 (LDS) -> MFMA gemm2 -> H2h/AS2/AD2
    hipLaunchKernelGGL(bucket_agg1_gemm2, dim3(nbuck), dim3(512), 0, stream,
                       ebuck, rows, nblk, N, Hh, AS1, AD1, b1,
                       W2, as2w, ad2w, H2h, AS2, AD2, ebuck2, rp2);
    // 3) aggregate layer-2 (fp32 out, bucket-slab CSR)
    hipLaunchKernelGGL(gat_aggregate2, dim3(nbAgg), dim3(256), 0, stream,
                       H2h, AS2, AD2, ebuck2, rp2, b2, out, N);
}

// Round 9
// 158.348 us; speedup vs baseline: 1.1233x; 1.0050x over previous
//
#include <hip/hip_runtime.h>
#include <cstddef>

constexpr int FIN = 128;
constexpr int EPB = 2048;   // edges per block in sort pass (391 blocks)
constexpr int BSH = 7;      // bucket shift: 128 nodes per bucket
constexpr int NPB = 128;    // nodes per bucket
constexpr int PACK_SH = 25; // pack: (dst_local << 25) | src (src < 2^25)
constexpr int SRCMASK = (1 << PACK_SH) - 1;
constexpr int RSTR = 512;   // rows matrix stride (nbuck+1 <= 512)
constexpr int CAP = 4608;   // per-bucket edge cap (mean 2048, sd ~45)
constexpr int RPS = NPB + 1; // per-bucket row-table stride (129)

typedef _Float16 half4 __attribute__((ext_vector_type(4)));
typedef _Float16 half8 __attribute__((ext_vector_type(8)));
typedef float floatx4 __attribute__((ext_vector_type(4)));

// ---------------------------------------------------------------------------
// Block-wide exclusive scan over NW waves (NW*64 threads); returns total.
// ---------------------------------------------------------------------------
template <int NW>
__device__ __forceinline__ int block_scan_tot(int v, int tid, int* wsums,
                                              int* tot) {
    int lane = tid & 63, w = tid >> 6;
    int x = v;
#pragma unroll
    for (int off = 1; off < 64; off <<= 1) {
        int y = __shfl_up(x, off, 64);
        if (lane >= off) x += y;
    }
    if (lane == 63) wsums[w] = x;
    __syncthreads();
    int add = 0, t = 0;
#pragma unroll
    for (int i = 0; i < NW; ++i) {
        add += (i < w) ? wsums[i] : 0;
        t += wsums[i];
    }
    *tot = t;
    return x + add - v;
}

// ---------------------------------------------------------------------------
// MFMA GEMM core (256 threads): W-stage + sync + MFMA + AS/AD epilogue + Hh.
// ---------------------------------------------------------------------------
template <int K>
__device__ __forceinline__
void gemm_core(const float* __restrict__ W, const float* __restrict__ ASRC,
               const float* __restrict__ ADST, _Float16* __restrict__ Hh,
               float* __restrict__ AS, float* __restrict__ AD, int N, int nb,
               _Float16* Xh, _Float16* WT) {
    constexpr int LDH = K + 8;
    const int tid = threadIdx.x;
    for (int i = tid; i < 64 * (K / 4); i += 256) {
        int n = i & 63, kg = i >> 6;
        half4 h;
#pragma unroll
        for (int j = 0; j < 4; ++j)
            h[j] = (_Float16)W[(4 * kg + j) * 64 + n];
        *(half4*)(WT + n * LDH + 4 * kg) = h;
    }
    __syncthreads();

    const int l = tid & 63;
    const int r0 = (tid >> 6) * 16;
    const int n16 = l & 15, quad = l >> 4;

    floatx4 acc[4];
#pragma unroll
    for (int nt = 0; nt < 4; ++nt) acc[nt] = (floatx4){0.f, 0.f, 0.f, 0.f};

#pragma unroll
    for (int k0 = 0; k0 < K; k0 += 32) {
        half8 a = *(const half8*)(Xh + (r0 + n16) * LDH + k0 + quad * 8);
#pragma unroll
        for (int nt = 0; nt < 4; ++nt) {
            half8 b = *(const half8*)(WT + (nt * 16 + n16) * LDH + k0 + quad * 8);
            acc[nt] = __builtin_amdgcn_mfma_f32_16x16x32_f16(a, b, acc[nt], 0, 0, 0);
        }
    }

    float pa[4] = {0.f, 0.f, 0.f, 0.f}, pd[4] = {0.f, 0.f, 0.f, 0.f};
#pragma unroll
    for (int nt = 0; nt < 4; ++nt) {
        float as_v = ASRC[nt * 16 + n16], ad_v = ADST[nt * 16 + n16];
#pragma unroll
        for (int reg = 0; reg < 4; ++reg) {
            pa[reg] += acc[nt][reg] * as_v;
            pd[reg] += acc[nt][reg] * ad_v;
        }
    }
#pragma unroll
    for (int off = 1; off < 16; off <<= 1) {
#pragma unroll
        for (int reg = 0; reg < 4; ++reg) {
            pa[reg] += __shfl_xor(pa[reg], off, 64);
            pd[reg] += __shfl_xor(pd[reg], off, 64);
        }
    }
    if (n16 == 0) {
#pragma unroll
        for (int reg = 0; reg < 4; ++reg) {
            int row = nb + r0 + quad * 4 + reg;
            if (row < N) { AS[row] = pa[reg]; AD[row] = pd[reg]; }
        }
    }

#pragma unroll
    for (int nt = 0; nt < 4; ++nt)
#pragma unroll
        for (int reg = 0; reg < 4; ++reg)
            Xh[(r0 + quad * 4 + reg) * LDH + nt * 16 + n16] = (_Float16)acc[nt][reg];
    {
        int r = r0 + (l >> 2);
        int o = (l & 3) * 16;
        if (nb + r < N) {
            half8 v0 = *(const half8*)(Xh + r * LDH + o);
            half8 v1 = *(const half8*)(Xh + r * LDH + o + 8);
            *(half8*)(Hh + (size_t)(nb + r) * 64 + o) = v0;
            *(half8*)(Hh + (size_t)(nb + r) * 64 + o + 8) = v1;
        }
    }
}

// gemm body with global X staging (layer 1)
template <int K, typename XT>
__device__ __forceinline__
void gemm_mfma_body(const XT* __restrict__ X, const float* __restrict__ W,
                    const float* __restrict__ ASRC, const float* __restrict__ ADST,
                    _Float16* __restrict__ Hh, float* __restrict__ AS,
                    float* __restrict__ AD, int N, int blk,
                    _Float16* Xh, _Float16* WT) {
    constexpr int LDH = K + 8;
    const int tid = threadIdx.x;
    const int nb = blk * 64;
    if constexpr (sizeof(XT) == 4) {
        constexpr int QPR = K / 4;
        for (int i = tid; i < 64 * QPR; i += 256) {
            int r = i / QPR, q = i % QPR;
            float4 v = make_float4(0.f, 0.f, 0.f, 0.f);
            if (nb + r < N) v = *(const float4*)(X + (size_t)(nb + r) * K + 4 * q);
            half4 h; h[0] = (_Float16)v.x; h[1] = (_Float16)v.y;
            h[2] = (_Float16)v.z; h[3] = (_Float16)v.w;
            *(half4*)(Xh + r * LDH + 4 * q) = h;
        }
    } else {
        constexpr int OPR = K / 8;
        for (int i = tid; i < 64 * OPR; i += 256) {
            int r = i / OPR, o = i % OPR;
            half8 v = {};
            if (nb + r < N) v = *(const half8*)(X + (size_t)(nb + r) * K + 8 * o);
            *(half8*)(Xh + r * LDH + 8 * o) = v;
        }
    }
    gemm_core<K>(W, ASRC, ADST, Hh, AS, AD, N, nb, Xh, WT);
}

// ---------------------------------------------------------------------------
// Dispatch 1: blocks [0, nblk) LDS-bucket-sort their 2048 edges into a
// block-PRIVATE ebuck slab (R2 lesson: scattered 4B cross-XCD writes are
// 16x amplified) and emit per-(blk,bucket) offsets (rows). Rest: gemm layer-1.
// ---------------------------------------------------------------------------
__global__ __launch_bounds__(256)
void gemm1_and_sort(const float* __restrict__ X, const float* __restrict__ W,
                    const float* __restrict__ ASRC, const float* __restrict__ ADST,
                    _Float16* __restrict__ Hh, float* __restrict__ AS,
                    float* __restrict__ AD, int N,
                    const int* __restrict__ src, const int* __restrict__ dst,
                    int E, int nblk, int nbuck,
                    int* __restrict__ rows, int* __restrict__ ebuck) {
    constexpr int K = FIN, LDH = K + 8;
    __shared__ _Float16 Xh[64 * LDH];
    __shared__ _Float16 WT[64 * LDH];
    __shared__ int wsums[4];

    const int tid = threadIdx.x;
    if ((int)blockIdx.x < nblk) {
        int* sorted = (int*)Xh;          // up to 2048 ints
        int* hist   = (int*)WT;          // 512 ints
        int* cur    = hist + 512;        // 512 ints
        for (int i = tid; i < nbuck; i += 256) hist[i] = 0;
        __syncthreads();

        const int e0 = blockIdx.x * EPB;
        const int e1 = min(e0 + EPB, E);
        const int cnt = e1 - e0;

        int pay[8], bk[8];
#pragma unroll
        for (int k = 0; k < 8; ++k) {
            int e = e0 + tid + k * 256;
            bk[k] = -1; pay[k] = 0;
            if (e < e1) {
                int d = dst[e];
                bk[k] = d >> BSH;
                pay[k] = ((d & (NPB - 1)) << PACK_SH) | src[e];
                atomicAdd(&hist[bk[k]], 1);
            }
        }
        __syncthreads();

        int i0 = 2 * tid, i1 = 2 * tid + 1;
        int v0 = (i0 < nbuck) ? hist[i0] : 0;
        int v1 = (i1 < nbuck) ? hist[i1] : 0;
        int tot;
        int ex = block_scan_tot<4>(v0 + v1, tid, wsums, &tot);
        if (i0 < nbuck) {
            cur[i0] = ex;
            rows[blockIdx.x * RSTR + i0] = ex;
        }
        if (i1 < nbuck) {
            cur[i1] = ex + v0;
            rows[blockIdx.x * RSTR + i1] = ex + v0;
        }
        if (tid == 0) rows[blockIdx.x * RSTR + nbuck] = cnt;
        __syncthreads();

#pragma unroll
        for (int k = 0; k < 8; ++k) {
            if (bk[k] >= 0) {
                int p = atomicAdd(&cur[bk[k]], 1);
                sorted[p] = pay[k];
            }
        }
        __syncthreads();
        for (int i = tid; i < cnt; i += 256)
            ebuck[blockIdx.x * EPB + i] = sorted[i];
        return;
    }
    gemm_mfma_body<K, float>(X, W, ASRC, ADST, Hh, AS, AD, N,
                             blockIdx.x - nblk, Xh, WT);
}

// ---------------------------------------------------------------------------
// Single-node full-wave aggregation (deg > 32 fallback, incl. deg > 64).
// LDSOUT: write node's 64-ch fp16 row to ldsX[(n&127)*72 + c].
// ---------------------------------------------------------------------------
template <bool LDSOUT, typename OT>
__device__ __forceinline__
void agg_one_node(const _Float16* __restrict__ Hh, const float* __restrict__ AS,
                  const float* __restrict__ AD, const int* __restrict__ csr_src,
                  const float* __restrict__ bias, OT* __restrict__ OUT,
                  _Float16* ldsX, int n, int base, int end, int lane, int relu) {
    const int cnt = end - base;
    const float adn = AD[n];

    if (cnt > 64) {   // rare scalar 2-pass path
        float m = -INFINITY;
        for (int c0 = base; c0 < end; c0 += 64) {
            int c = min(64, end - c0);
            float e = -INFINITY;
            if (lane < c) {
                int sr = csr_src[c0 + lane];
                float t = AS[sr] + adn;
                e = t > 0.f ? t : 0.2f * t;
            }
#pragma unroll
            for (int off = 32; off > 0; off >>= 1) e = fmaxf(e, __shfl_xor(e, off, 64));
            m = fmaxf(m, e);
        }
        float s = 0.f, acc = 0.f;
        for (int c0 = base; c0 < end; c0 += 64) {
            int c = min(64, end - c0);
            int srcl = 0;
            float p = 0.f;
            if (lane < c) {
                srcl = csr_src[c0 + lane];
                float t = AS[srcl] + adn;
                t = t > 0.f ? t : 0.2f * t;
                p = __expf(t - m);
            }
            float cs = p;
#pragma unroll
            for (int off = 32; off > 0; off >>= 1) cs += __shfl_xor(cs, off, 64);
            s += cs;
            for (int j = 0; j < c; ++j)
                acc += __shfl(p, j, 64) *
                       (float)Hh[(size_t)__shfl(srcl, j, 64) * 64 + lane];
        }
        float o = acc * (1.f / (s + 1e-16f)) + bias[lane];
        if (relu) o = fmaxf(o, 0.f);
        if constexpr (LDSOUT) ldsX[(n & (NPB - 1)) * 72 + lane] = (_Float16)o;
        else OUT[(size_t)n * 64 + lane] = (OT)o;
        return;
    }

    // deg <= 64 full-wave path
    int srcl = 0;
    float el = 0.f;
    if (lane < cnt) {
        srcl = csr_src[base + lane];
        float e = AS[srcl] + adn;
        el = e > 0.f ? e : 0.2f * e;
    }
    float p = (lane < cnt) ? __expf(el) : 0.f;
    float s = p;
#pragma unroll
    for (int off = 32; off > 0; off >>= 1) s += __shfl_xor(s, off, 64);
    const float inv = 1.f / (s + 1e-16f);

    const int eg = lane >> 3;
    const int c8 = (lane & 7) * 8;

    float acc[8], acc2[8];
#pragma unroll
    for (int t = 0; t < 8; ++t) { acc[t] = 0.f; acc2[t] = 0.f; }

    int j = 0;
    for (; j + 16 <= cnt; j += 16) {
        int iA = j + eg, iB = j + 8 + eg;
        int sA = __shfl(srcl, iA, 64), sB = __shfl(srcl, iB, 64);
        float aA = __shfl(p, iA, 64),  aB = __shfl(p, iB, 64);
        half8 hA = *(const half8*)(Hh + (size_t)sA * 64 + c8);
        half8 hB = *(const half8*)(Hh + (size_t)sB * 64 + c8);
#pragma unroll
        for (int t = 0; t < 8; ++t) {
            acc[t]  += aA * (float)hA[t];
            acc2[t] += aB * (float)hB[t];
        }
    }
    for (; j < cnt; j += 8) {
        int iA = j + eg;
        int sA = __shfl(srcl, iA, 64);
        float aA = __shfl(p, iA, 64);
        half8 hA = *(const half8*)(Hh + (size_t)sA * 64 + c8);
#pragma unroll
        for (int t = 0; t < 8; ++t) acc[t] += aA * (float)hA[t];
    }
#pragma unroll
    for (int t = 0; t < 8; ++t) acc[t] += acc2[t];
#pragma unroll
    for (int off = 8; off <= 32; off <<= 1)
#pragma unroll
        for (int t = 0; t < 8; ++t) acc[t] += __shfl_xor(acc[t], off, 64);

    if (lane < 8) {
        float4 b0 = *(const float4*)(bias + c8);
        float4 b1 = *(const float4*)(bias + c8 + 4);
        float o[8];
        o[0] = acc[0] * inv + b0.x; o[1] = acc[1] * inv + b0.y;
        o[2] = acc[2] * inv + b0.z; o[3] = acc[3] * inv + b0.w;
        o[4] = acc[4] * inv + b1.x; o[5] = acc[5] * inv + b1.y;
        o[6] = acc[6] * inv + b1.z; o[7] = acc[7] * inv + b1.w;
        if (relu) {
#pragma unroll
            for (int t = 0; t < 8; ++t) o[t] = fmaxf(o[t], 0.f);
        }
        if constexpr (LDSOUT) {
            half8 hv;
#pragma unroll
            for (int t = 0; t < 8; ++t) hv[t] = (_Float16)o[t];
            *(half8*)(ldsX + (n & (NPB - 1)) * 72 + c8) = hv;
        } else if constexpr (sizeof(OT) == 2) {
            half8 hv;
#pragma unroll
            for (int t = 0; t < 8; ++t) hv[t] = (_Float16)o[t];
            *(half8*)((_Float16*)OUT + (size_t)n * 64 + c8) = hv;
        } else {
            *(float4*)((float*)OUT + (size_t)n * 64 + c8) =
                make_float4(o[0], o[1], o[2], o[3]);
            *(float4*)((float*)OUT + (size_t)n * 64 + c8 + 4) =
                make_float4(o[4], o[5], o[6], o[7]);
        }
    }
}

// ---------------------------------------------------------------------------
// Paired (2 nodes per wave) softmax+aggregate; base/end supplied per-lane.
// LDSOUT: output rows to ldsX[(n&127)*72].
// ---------------------------------------------------------------------------
template <bool LDSOUT, typename OT>
__device__ __forceinline__
void agg_pair_core(const _Float16* __restrict__ Hh, const float* __restrict__ AS,
                   const float* __restrict__ AD, const int* __restrict__ csr,
                   const float* __restrict__ bias, OT* __restrict__ OUT,
                   _Float16* ldsX, int n, int N, int relu, int lane,
                   int base, int end) {
    const int l32 = lane & 31;
    const int cnt = end - base;

    if (!__all(cnt <= 32)) {
        int baseA = __shfl(base, 0, 64),  endA = __shfl(end, 0, 64);
        int baseB = __shfl(base, 32, 64), endB = __shfl(end, 32, 64);
        int nA = __shfl(n, 0, 64), nB = __shfl(n, 32, 64);
        if (nA < N) agg_one_node<LDSOUT, OT>(Hh, AS, AD, csr, bias, OUT, ldsX,
                                             nA, baseA, endA, lane, relu);
        if (nB < N) agg_one_node<LDSOUT, OT>(Hh, AS, AD, csr, bias, OUT, ldsX,
                                             nB, baseB, endB, lane, relu);
        return;
    }

    const float adn = (n < N) ? AD[n] : 0.f;
    int srcl = 0;
    float p = 0.f;
    if (l32 < cnt) {
        srcl = csr[base + l32];
        float e = AS[srcl] + adn;
        e = e > 0.f ? e : 0.2f * e;
        p = __expf(e);
    }
    float s = p;
#pragma unroll
    for (int off = 16; off > 0; off >>= 1) s += __shfl_xor(s, off, 64);
    const float inv = 1.f / (s + 1e-16f);

    const int eg = l32 >> 3;
    const int c8 = (l32 & 7) * 8;

    float acc[8], acc2[8];
#pragma unroll
    for (int t = 0; t < 8; ++t) { acc[t] = 0.f; acc2[t] = 0.f; }

    int j = 0;
    for (; j + 8 <= cnt; j += 8) {
        int iA = j + eg, iB = j + 4 + eg;
        int sA = __shfl(srcl, iA, 32), sB = __shfl(srcl, iB, 32);
        float aA = __shfl(p, iA, 32),  aB = __shfl(p, iB, 32);
        half8 hA = *(const half8*)(Hh + (size_t)sA * 64 + c8);
        half8 hB = *(const half8*)(Hh + (size_t)sB * 64 + c8);
#pragma unroll
        for (int t = 0; t < 8; ++t) {
            acc[t]  += aA * (float)hA[t];
            acc2[t] += aB * (float)hB[t];
        }
    }
    for (; j < cnt; j += 4) {
        int iA = j + eg;
        int sA = __shfl(srcl, iA, 32);
        float aA = __shfl(p, iA, 32);
        half8 hA = *(const half8*)(Hh + (size_t)sA * 64 + c8);
#pragma unroll
        for (int t = 0; t < 8; ++t) acc[t] += aA * (float)hA[t];
    }
#pragma unroll
    for (int t = 0; t < 8; ++t) acc[t] += acc2[t];
#pragma unroll
    for (int t = 0; t < 8; ++t) acc[t] += __shfl_xor(acc[t], 8, 64);
#pragma unroll
    for (int t = 0; t < 8; ++t) acc[t] += __shfl_xor(acc[t], 16, 64);

    if (l32 < 8 && n < N) {
        float4 b0 = *(const float4*)(bias + c8);
        float4 b1 = *(const float4*)(bias + c8 + 4);
        float o[8];
        o[0] = acc[0] * inv + b0.x; o[1] = acc[1] * inv + b0.y;
        o[2] = acc[2] * inv + b0.z; o[3] = acc[3] * inv + b0.w;
        o[4] = acc[4] * inv + b1.x; o[5] = acc[5] * inv + b1.y;
        o[6] = acc[6] * inv + b1.z; o[7] = acc[7] * inv + b1.w;
        if (relu) {
#pragma unroll
            for (int t = 0; t < 8; ++t) o[t] = fmaxf(o[t], 0.f);
        }
        if constexpr (LDSOUT) {
            half8 hv;
#pragma unroll
            for (int t = 0; t < 8; ++t) hv[t] = (_Float16)o[t];
            *(half8*)(ldsX + (n & (NPB - 1)) * 72 + c8) = hv;
        } else if constexpr (sizeof(OT) == 2) {
            half8 hv;
#pragma unroll
            for (int t = 0; t < 8; ++t) hv[t] = (_Float16)o[t];
            *(half8*)((_Float16*)OUT + (size_t)n * 64 + c8) = hv;
        } else {
            *(float4*)((float*)OUT + (size_t)n * 64 + c8) =
                make_float4(o[0], o[1], o[2], o[3]);
            *(float4*)((float*)OUT + (size_t)n * 64 + c8 + 4) =
                make_float4(o[4], o[5], o[6], o[7]);
        }
    }
}

// ---------------------------------------------------------------------------
// Dispatch 2 (R9): per-bucket sort + layer-1 aggregate INTO LDS X-tile
// + layer-2 MFMA gemm (two 64-row tiles). R9 change: q-loop unroll 2 —
// interleaves two independent pair computations per wave to double in-wave
// MLP in the latency-bound gather phase (R8 was unroll 1; R4/R5's build bomb
// was unroll 8 = 16 agg_one_node copies; 2x -> 4 copies, same order as R3/R7
// which built fine).
// ---------------------------------------------------------------------------
__global__ __launch_bounds__(512)
void bucket_agg1_gemm2(const int* __restrict__ ebuck, const int* __restrict__ rows,
                       int nblk, int N,
                       const _Float16* __restrict__ Hh, const float* __restrict__ AS1,
                       const float* __restrict__ AD1, const float* __restrict__ b1,
                       const float* __restrict__ W2, const float* __restrict__ as2w,
                       const float* __restrict__ ad2w, _Float16* __restrict__ H2h,
                       float* __restrict__ AS2, float* __restrict__ AD2,
                       int* __restrict__ ebuck2, int* __restrict__ rp2) {
    __shared__ int eLX[CAP];           // phase A: edge staging; phase B: Xh[128][72] fp16
    __shared__ int eS[CAP];
    __shared__ _Float16 WT[64 * 72];   // W2^T, shared by both tiles
    __shared__ int hist[NPB];
    __shared__ int cur[NPB];
    __shared__ int rowr[RPS];
    __shared__ int wsums[8];
    __shared__ int cursor;
    const int b = blockIdx.x, tid = threadIdx.x;

    // stage W2^T early (independent of everything else)
    for (int i = tid; i < 64 * 16; i += 512) {
        int n = i & 63, kg = i >> 6;
        half4 h;
#pragma unroll
        for (int j = 0; j < 4; ++j)
            h[j] = (_Float16)W2[(4 * kg + j) * 64 + n];
        *(half4*)(WT + n * 72 + 4 * kg) = h;
    }
    if (tid < NPB) hist[tid] = 0;
    if (tid == 0) cursor = 0;
    __syncthreads();

    // gather this bucket's segments from K1's private slabs
    for (int blk = tid; blk < nblk; blk += 512) {
        int r0 = rows[blk * RSTR + b];
        int r1 = rows[blk * RSTR + b + 1];
        int len = r1 - r0;
        if (len > 0) {
            int ofs = atomicAdd(&cursor, len);
            for (int i = 0; i < len; ++i)
                if (ofs + i < CAP) eLX[ofs + i] = ebuck[blk * EPB + r0 + i];
        }
    }
    __syncthreads();
    const int btot = min(cursor, CAP);

    for (int e = tid; e < btot; e += 512)
        atomicAdd(&hist[((unsigned)eLX[e]) >> PACK_SH], 1);
    __syncthreads();
    int v = (tid < NPB) ? hist[tid] : 0;
    int tot;
    int excl = block_scan_tot<8>(v, tid, wsums, &tot);
    if (tid < NPB) { cur[tid] = excl; rowr[tid] = excl; }
    if (tid == 0) rowr[NPB] = btot;
    __syncthreads();
    for (int e = tid; e < btot; e += 512) {
        int pv = eLX[e];
        int p = atomicAdd(&cur[((unsigned)pv) >> PACK_SH], 1);
        eS[p] = pv & SRCMASK;
    }
    __syncthreads();                   // eLX (eL role) now dead

    // publish bucket CSR for the layer-2 aggregate (block-private, coalesced)
    for (int i = tid; i < btot; i += 512)
        ebuck2[(size_t)b * CAP + i] = eS[i];
    for (int j = tid; j < RPS; j += 512)
        rp2[b * RPS + j] = rowr[j];

    // zero Xh (covers out-of-range rows of the last bucket)
    _Float16* Xh = (_Float16*)eLX;
    for (int i = tid; i < 128 * 72 / 8; i += 512)
        ((half8*)Xh)[i] = (half8){};
    __syncthreads();

    // layer-1 aggregate: 8 waves x 8 pairs = 128 nodes, output into Xh.
    // unroll 2: two independent pairs in flight per wave (gather MLP x2).
    const int lane = tid & 63, w = tid >> 6;
    const int half = lane >> 5;
#pragma unroll 2
    for (int q = 0; q < 8; ++q) {
        int nloc = w * 16 + q * 2 + half;
        int n = (b << BSH) + nloc;
        int base = rowr[nloc], end = rowr[nloc + 1];
        agg_pair_core<true, _Float16>(Hh, AS1, AD1, (const int*)eS, b1,
                                      (_Float16*)nullptr, Xh, n, N, 1, lane,
                                      base, end);
    }
    __syncthreads();                   // all Xh rows written before MFMA

    // layer-2 MFMA: two 64-row tiles (tile = tid>>8), shared WT
    const int tt = tid & 255;
    const int tile = tid >> 8;
    const int nb = (b << BSH) + tile * 64;
    _Float16* Xt = Xh + tile * 64 * 72;

    const int l = tt & 63;
    const int r0 = (tt >> 6) * 16;
    const int n16 = l & 15, quad = l >> 4;

    floatx4 acc[4];
#pragma unroll
    for (int nt = 0; nt < 4; ++nt) acc[nt] = (floatx4){0.f, 0.f, 0.f, 0.f};

#pragma unroll
    for (int k0 = 0; k0 < 64; k0 += 32) {
        half8 a = *(const half8*)(Xt + (r0 + n16) * 72 + k0 + quad * 8);
#pragma unroll
        for (int nt = 0; nt < 4; ++nt) {
            half8 bb = *(const half8*)(WT + (nt * 16 + n16) * 72 + k0 + quad * 8);
            acc[nt] = __builtin_amdgcn_mfma_f32_16x16x32_f16(a, bb, acc[nt], 0, 0, 0);
        }
    }

    float pa[4] = {0.f, 0.f, 0.f, 0.f}, pd[4] = {0.f, 0.f, 0.f, 0.f};
#pragma unroll
    for (int nt = 0; nt < 4; ++nt) {
        float as_v = as2w[nt * 16 + n16], ad_v = ad2w[nt * 16 + n16];
#pragma unroll
        for (int reg = 0; reg < 4; ++reg) {
            pa[reg] += acc[nt][reg] * as_v;
            pd[reg] += acc[nt][reg] * ad_v;
        }
    }
#pragma unroll
    for (int off = 1; off < 16; off <<= 1) {
#pragma unroll
        for (int reg = 0; reg < 4; ++reg) {
            pa[reg] += __shfl_xor(pa[reg], off, 64);
            pd[reg] += __shfl_xor(pd[reg], off, 64);
        }
    }
    if (n16 == 0) {
#pragma unroll
        for (int reg = 0; reg < 4; ++reg) {
            int row = nb + r0 + quad * 4 + reg;
            if (row < N) { AS2[row] = pa[reg]; AD2[row] = pd[reg]; }
        }
    }

#pragma unroll
    for (int nt = 0; nt < 4; ++nt)
#pragma unroll
        for (int reg = 0; reg < 4; ++reg)
            Xt[(r0 + quad * 4 + reg) * 72 + nt * 16 + n16] = (_Float16)acc[nt][reg];
    {
        int r = r0 + (l >> 2);
        int o = (l & 3) * 16;
        if (nb + r < N) {
            half8 v0 = *(const half8*)(Xt + r * 72 + o);
            half8 v1 = *(const half8*)(Xt + r * 72 + o + 8);
            *(half8*)(H2h + (size_t)(nb + r) * 64 + o) = v0;
            *(half8*)(H2h + (size_t)(nb + r) * 64 + o + 8) = v1;
        }
    }
}

// ---------------------------------------------------------------------------
// Dispatch 3: standalone paired aggregate (layer 2, fp32 out), indexing the
// bucket-slab CSR (25000 waves — max latency hiding).
// ---------------------------------------------------------------------------
__global__ __launch_bounds__(256)
void gat_aggregate2(const _Float16* __restrict__ Hh, const float* __restrict__ AS,
                    const float* __restrict__ AD, const int* __restrict__ ebuck2,
                    const int* __restrict__ rp2, const float* __restrict__ bias,
                    float* __restrict__ OUT, int N) {
    const int lane = threadIdx.x & 63;
    const int half = lane >> 5;
    const int pair0 = blockIdx.x * 8 + (threadIdx.x >> 6) * 2;
    if (pair0 >= N) return;
    const int n = pair0 + half;
    int base = 0, end = 0;
    if (n < N) {
        int b = n >> BSH, j = n & (NPB - 1);
        base = b * CAP + rp2[b * RPS + j];
        end  = b * CAP + rp2[b * RPS + j + 1];
    }
    agg_pair_core<false, float>(Hh, AS, AD, ebuck2, bias, OUT,
                                (_Float16*)nullptr, n, N, 0, lane, base, end);
}

// ---------------------------------------------------------------------------
extern "C" void kernel_launch(void* const* d_in, const int* in_sizes, int n_in,
                              void* d_out, int out_size, void* d_ws, size_t ws_size,
                              hipStream_t stream) {
    const float* x    = (const float*)d_in[0];
    const int*   ei   = (const int*)d_in[1];
    const float* W1   = (const float*)d_in[2];
    const float* as1w = (const float*)d_in[3];
    const float* ad1w = (const float*)d_in[4];
    const float* b1   = (const float*)d_in[5];
    const float* W2   = (const float*)d_in[6];
    const float* as2w = (const float*)d_in[7];
    const float* ad2w = (const float*)d_in[8];
    const float* b2   = (const float*)d_in[9];
    float* out = (float*)d_out;

    const int N = in_sizes[0] / FIN;   // 50000
    const int E = in_sizes[1] / 2;     // 800000
    const int* esrc = ei;
    const int* edst = ei + E;

    const int nbuck = (N + NPB - 1) >> BSH;      // 391
    const int nblk  = (E + EPB - 1) / EPB;       // 391

    char* wp8 = (char*)d_ws;
    _Float16* Hh  = (_Float16*)wp8;  wp8 += (size_t)N * 64 * 2;   // layer-1 h
    _Float16* H2h = (_Float16*)wp8;  wp8 += (size_t)N * 64 * 2;   // layer-2 h
    float* AS1 = (float*)wp8;        wp8 += (size_t)N * 4;
    float* AD1 = (float*)wp8;        wp8 += (size_t)N * 4;
    float* AS2 = (float*)wp8;        wp8 += (size_t)N * 4;
    float* AD2 = (float*)wp8;        wp8 += (size_t)N * 4;
    int* ebuck  = (int*)wp8;         wp8 += (size_t)nblk * EPB * 4;
    int* rows   = (int*)wp8;         wp8 += (size_t)nblk * RSTR * 4;
    int* ebuck2 = (int*)wp8;         wp8 += (size_t)nbuck * CAP * 4;
    int* rp2    = (int*)wp8;         wp8 += (size_t)nbuck * RPS * 4;

    const int nbG = (N + 63) / 64;               // 782
    const int nbAgg = (N + 7) / 8;               // 6250

    // 1) fused: LDS bucket-sort (391 blocks) + MFMA gemm layer-1
    hipLaunchKernelGGL(gemm1_and_sort, dim3(nblk + nbG), dim3(256), 0, stream,
                       x, W1, as1w, ad1w, Hh, AS1, AD1, N,
                       esrc, edst, E, nblk, nbuck, rows, ebuck);
    // 2) per-bucket: sort -> agg1 (LDS, unroll-2 pairs) -> MFMA gemm2
    hipLaunchKernelGGL(bucket_agg1_gemm2, dim3(nbuck), dim3(512), 0, stream,
                       ebuck, rows, nblk, N, Hh, AS1, AD1, b1,
                       W2, as2w, ad2w, H2h, AS2, AD2, ebuck2, rp2);
    // 3) aggregate layer-2 (fp32 out, bucket-slab CSR)
    hipLaunchKernelGGL(gat_aggregate2, dim3(nbAgg), dim3(256), 0, stream,
                       H2h, AS2, AD2, ebuck2, rp2, b2, out, N);
}